// Round 10
// baseline (184.928 us; speedup 1.0000x reference)
//
#include <hip/hip_runtime.h>
#include <cstdint>
#include <cstddef>

typedef unsigned int u32;
typedef unsigned long long u64;

#define NTOT 122740      // total proposals (records) per batch
#define NPAIR 61370
#define KTOP 1024        // top-K kept per batch (deterministic bin-cutoff set)
#define WIN  256         // IoU-matrix window over the sorted list
#define NBIN 4096
#define SCORE_T 0.25f
#define TBITS 0x3E800000u       // bit pattern of 0.25f

// range thresholds on score bits (bin boundaries 3584/3072/2560/2048)
#define RT0 0x3F5DF000u   // bin >= 3584
#define RT1 0x3F3FF000u   // bin >= 3072
#define RT2 0x3F1FF000u   // bin >= 2560
#define RT3 0x3EFFF000u   // bin >= 2048

#define CSTRIDE 128             // counters per batch (u32); counter r at r*16 (64B apart)
#define DONE_SLOT 100           // counters[DONE_SLOT] = worker-done counter (batch-0 region, unused slot)
// per-batch range capacities and offsets (entries)
#define CAP0 4096
#define CAP1 8192
#define CAP2 12288
#define CAP3 16384
#define CAP4 16384
#define OFF0 0
#define OFF1 4096
#define OFF2 12288
#define OFF3 24576
#define OFF4 40960
#define BATCH_ENT 57344

// concatenated float4 layout per batch (all level boundaries are f4-aligned):
//   L2: f4 [0,      138624)  p2, batch stride 138624 f4
//   L3: f4 [138624, 173280)  p3, stride 34656
//   L4: f4 [173280, 181944)  p4, stride 8664
//   L5: f4 [181944, 184110)  p5, stride 2166
#define F4TOT 184110
#define F4B3 138624
#define F4B4 173280
#define F4B5 181944

// ws layout (bytes):
//   counters: 32*128*4        = 16384     @ 0
//   cand:     32*57344*8      = 14680064  @ 16384   (~14.7 MB total)
#define WS_CAND 16384

// ---------------------------------------------------------------- helpers
__device__ __forceinline__ float sigm(float x) { return 1.0f / (1.0f + expf(-x)); }

__device__ __forceinline__ int score_bin(u32 bits) {
  return min(4095, 1 + (int)((bits - TBITS) >> 12));
}

__device__ __forceinline__ u64 shfl_u64(u64 x, int src) {
  int lo = __shfl((int)(u32)x, src, 64);
  int hi = __shfl((int)(u32)(x >> 32), src, 64);
  return ((u64)(u32)hi << 32) | (u32)lo;
}

// fallback-only: scores for record pair P (records 2P, 2P+1) of batch b
__device__ __forceinline__ void score_pair(int P, int b,
    const float* __restrict__ p2, const float* __restrict__ p3,
    const float* __restrict__ p4, const float* __restrict__ p5,
    u32& b0, u32& b1, u32& gi0, u32& gi1)
{
  int t0 = 2 * P;
  const float* p; int l0, LN;
  if (t0 < 92416)       { p = p2; l0 = t0;          LN = 92416; }
  else if (t0 < 115520) { p = p3; l0 = t0 - 92416;  LN = 23104; }
  else if (t0 < 121296) { p = p4; l0 = t0 - 115520; LN = 5776;  }
  else                  { p = p5; l0 = t0 - 121296; LN = 1444;  }
  const float* q = p + ((size_t)b * LN + (size_t)l0) * 6;
  float4 v1 = *(const float4*)(q + 4);
  float4 v2 = *(const float4*)(q + 8);
  float s0 = sigm(v1.x) * sigm(v1.y);
  float s1 = sigm(v2.z) * sigm(v2.w);
  b0 = (s0 >= SCORE_T) ? __float_as_uint(s0) : 0u;
  b1 = (s1 >= SCORE_T) ? __float_as_uint(s1) : 0u;
  gi0 = (u32)t0; gi1 = (u32)(t0 + 1);
}

__device__ float4 decode_box_from_gidx(u32 gidx, int b,
    const float* __restrict__ p2, const float* __restrict__ p3,
    const float* __restrict__ p4, const float* __restrict__ p5)
{
  const float* p; int t, H, W; float stride;
  float aw0, ah0, aw1, ah1, aw2, ah2, aw3, ah3;
  if (gidx < 92416u) {
    p = p2 + (size_t)b * 92416 * 6; t = (int)gidx; H = 152; W = 152; stride = 4.0f;
    aw0=12.f; ah0=16.f; aw1=19.f; ah1=36.f; aw2=40.f; ah2=28.f; aw3=36.f; ah3=75.f;
  } else if (gidx < 115520u) {
    p = p3 + (size_t)b * 23104 * 6; t = (int)(gidx - 92416u); H = 76; W = 76; stride = 8.0f;
    aw0=36.f; ah0=75.f; aw1=76.f; ah1=55.f; aw2=72.f; ah2=146.f; aw3=142.f; ah3=110.f;
  } else if (gidx < 121296u) {
    p = p4 + (size_t)b * 5776 * 6; t = (int)(gidx - 115520u); H = 38; W = 38; stride = 16.0f;
    aw0=72.f; ah0=146.f; aw1=142.f; ah1=110.f; aw2=192.f; ah2=243.f; aw3=459.f; ah3=401.f;
  } else {
    p = p5 + (size_t)b * 1444 * 6; t = (int)(gidx - 121296u); H = 19; W = 19; stride = 32.0f;
    aw0=142.f; ah0=110.f; aw1=192.f; ah1=243.f; aw2=300.f; ah2=300.f; aw3=459.f; ah3=401.f;
  }
  int HW = H * W;
  int a = t / HW;
  int r = t - a * HW;
  int y = r / W;
  int x = r - y * W;
  const float* q = p + (size_t)t * 6;
  float2 t01 = *(const float2*)(q + 0);
  float2 t23 = *(const float2*)(q + 2);
  float cx = (sigm(t01.x) + (float)x) * stride;
  float cy = (sigm(t01.y) + (float)y) * stride;
  float aw = (a == 0) ? aw0 : (a == 1) ? aw1 : (a == 2) ? aw2 : aw3;
  float ah = (a == 0) ? ah0 : (a == 1) ? ah1 : (a == 2) ? ah2 : ah3;
  float bw = expf(t23.x) * aw;
  float bh = expf(t23.y) * ah;
  return make_float4(cx - 0.5f * bw, cy - 0.5f * bh, cx + 0.5f * bw, cy + 0.5f * bh);
}

__device__ __forceinline__ bool iou_gt(float4 A, float4 B) {
  float ltx = fmaxf(A.x, B.x), lty = fmaxf(A.y, B.y);
  float rbx = fminf(A.z, B.z), rby = fminf(A.w, B.w);
  float w = fmaxf(rbx - ltx, 0.0f), h = fmaxf(rby - lty, 0.0f);
  float inter = w * h;
  float a1 = fmaxf(A.z - A.x, 0.0f) * fmaxf(A.w - A.y, 0.0f);
  float a2 = fmaxf(B.z - B.x, 0.0f) * fmaxf(B.w - B.y, 0.0f);
  float iou = inter / (a1 + a2 - inter + 1e-9f);
  return iou > 0.5f;
}

// ---------------------------------------------------------------- A: decode + 5-range classify
// grid (120, 32), 512 thr, 1024 records/block. Dense f4 staging (fully coalesced),
// stride-1 consume, in-LDS partition into 5 range segments, one global atomic per
// range per block, coalesced flush.  (unchanged from round 9)
__global__ __launch_bounds__(512)
void decode_kernel(const float* __restrict__ p2, const float* __restrict__ p3,
                   const float* __restrict__ p4, const float* __restrict__ p5,
                   u32* __restrict__ counters, uint2* __restrict__ cand)
{
  __shared__ float4 sbuf4[1536];          // 24 KB  (1024 records)
  __shared__ uint2 stg[1024];             // 8 KB   partitioned survivors
  __shared__ u32 lcnt[8], lseg[8], lrank[8], gbase[8];
  const int tid = threadIdx.x;
  const int b = blockIdx.y;
  if (tid < 8) { lcnt[tid] = 0u; lrank[tid] = 0u; gbase[tid] = 0u; }

  const int rbase = blockIdx.x * 1024;
  const int FS = blockIdx.x * 1536;
  const float4* q2 = (const float4*)p2;
  const float4* q3 = (const float4*)p3;
  const float4* q4 = (const float4*)p4;
  const float4* q5 = (const float4*)p5;
  #pragma unroll
  for (int j = 0; j < 3; ++j) {
    int idx4 = FS + j * 512 + tid;
    if (idx4 < F4TOT) {
      const float4* src;
      if (idx4 < F4B3)      src = q2 + (size_t)b * 138624 + idx4;
      else if (idx4 < F4B4) src = q3 + (size_t)b * 34656  + (idx4 - F4B3);
      else if (idx4 < F4B5) src = q4 + (size_t)b * 8664   + (idx4 - F4B4);
      else                  src = q5 + (size_t)b * 2166   + (idx4 - F4B5);
      sbuf4[j * 512 + tid] = *src;
    }
  }
  __syncthreads();

  const float* sbuf = (const float*)sbuf4;
  u32 kb[2]; u32 kg[2]; int kr[2];
  #pragma unroll
  for (int k = 0; k < 2; ++k) {
    kb[k] = 0u; kr[k] = -1;
    int lr = tid + k * 512;
    int rg = rbase + lr;
    kg[k] = (u32)rg;
    if (rg < NTOT) {
      float2 cc = *(const float2*)&sbuf[lr * 6 + 4];
      float s = sigm(cc.x) * sigm(cc.y);
      if (s >= SCORE_T) {
        u32 bb = __float_as_uint(s);
        kb[k] = bb;
        int r;
        if      (bb >= RT0) r = 0;
        else if (bb >= RT1) r = 1;
        else if (bb >= RT2) r = 2;
        else if (bb >= RT3) r = 3;
        else                r = 4;
        kr[k] = r;
        atomicAdd(&lcnt[r], 1u);
      }
    }
  }
  __syncthreads();
  if (tid == 0) {
    u32 s = 0;
    #pragma unroll
    for (int r = 0; r < 5; ++r) { lseg[r] = s; s += lcnt[r]; }
  }
  if (tid < 5 && lcnt[tid]) gbase[tid] = atomicAdd(&counters[(size_t)b * CSTRIDE + tid * 16], lcnt[tid]);
  __syncthreads();
  #pragma unroll
  for (int k = 0; k < 2; ++k) {
    if (kr[k] >= 0) {
      u32 rk = atomicAdd(&lrank[kr[k]], 1u);
      stg[lseg[kr[k]] + rk] = make_uint2(kb[k], kg[k]);
    }
  }
  __syncthreads();
  uint2* cb = cand + (size_t)b * BATCH_ENT;
  const u32 roff[5] = { OFF0, OFF1, OFF2, OFF3, OFF4 };
  const u32 rcap[5] = { CAP0, CAP1, CAP2, CAP3, CAP4 };
  #pragma unroll
  for (int r = 0; r < 5; ++r) {
    const u32 cnt = lcnt[r], sg = lseg[r], gb = gbase[r];
    for (u32 i = tid; i < cnt; i += 512) {
      u32 d = gb + i;
      if (d < rcap[r]) cb[roff[r] + d] = stg[sg + i];
    }
  }
}

// ---------------------------------------------------------------- M: backend + DVFS heaters
// 256 blocks. Blocks 0..31: exact round-9 backend (range-pruned hist+scan+sort+NMS).
// Blocks 32..255: bounded FMA spin keeping all CUs busy so the clock stays boosted
// while the serial backend runs; they exit when all 32 workers signal done.
__global__ __launch_bounds__(1024, 1)
void mega_kernel(u32* __restrict__ counters, const uint2* __restrict__ cand,
                 const float* __restrict__ p2, const float* __restrict__ p3,
                 const float* __restrict__ p4, const float* __restrict__ p5,
                 float* __restrict__ out)
{
  const int bid = blockIdx.x;
  const int tid = threadIdx.x;

  // ================= heater path =================
  if (bid >= 32) {
    float acc = (float)tid * 0.001f + (float)bid;
    // bounded: <= 4000 outer iters (~ <1 ms worst case); poll done-counter each iter
    for (int o = 0; o < 4000; ++o) {
      u32 d = atomicAdd(&counters[DONE_SLOT], 0u);   // device-scope load
      if (d >= 32u) break;
      #pragma unroll 8
      for (int i = 0; i < 1024; ++i) acc = fmaf(acc, 1.0000001f, 0.0000001f);
    }
    if (acc == -1.0f) atomicAdd(&counters[DONE_SLOT + 1], 1u);  // keep acc alive; never true
    return;
  }

  // ================= worker path (identical to round 9) =================
  const int b = bid;

  __shared__ u32 sstart[NBIN];            // 16 KB
  __shared__ u32 scur[NBIN];              // 16 KB
  __shared__ u64 skey[KTOP];              // 8 KB
  __shared__ u64 skey2[KTOP];             // 8 KB
  __shared__ float4 sbox[WIN];            // 4 KB
  __shared__ u64 smat[WIN * 4];           // 8 KB
  __shared__ float4 selbox[100];          // 1.6 KB
  __shared__ int s_misc[4];
  __shared__ int s_B, s_n;

  const u32 c0 = counters[(size_t)b * CSTRIDE +  0];
  const u32 c1 = counters[(size_t)b * CSTRIDE + 16];
  const u32 c2 = counters[(size_t)b * CSTRIDE + 32];
  const u32 c3 = counters[(size_t)b * CSTRIDE + 48];
  const u32 c4 = counters[(size_t)b * CSTRIDE + 64];
  const u32 total = c0 + c1 + c2 + c3 + c4;
  const u32 need = min((u32)KTOP, total);
  int RL = 0;
  { u32 cum = c0;
    if (cum < need) { RL = 1; cum += c1; }
    if (cum < need) { RL = 2; cum += c2; }
    if (cum < need) { RL = 3; cum += c3; }
    if (cum < need) { RL = 4; cum += c4; }
  }
  const bool fb = (c0 > (u32)CAP0)
               || (RL >= 1 && c1 > (u32)CAP1)
               || (RL >= 2 && c2 > (u32)CAP2)
               || (RL >= 3 && c3 > (u32)CAP3)
               || (RL >= 4 && c4 > (u32)CAP4);

  for (int i = tid; i < NBIN; i += 1024) scur[i] = 0u;
  __syncthreads();

  const uint2* cb = cand + (size_t)b * BATCH_ENT;

  // ---- hist (read ranges 0..RL)
  if (!fb) {
    for (u32 i = tid; i < c0; i += 1024) atomicAdd(&scur[score_bin(cb[OFF0 + i].x)], 1u);
    if (RL >= 1) for (u32 i = tid; i < c1; i += 1024) atomicAdd(&scur[score_bin(cb[OFF1 + i].x)], 1u);
    if (RL >= 2) for (u32 i = tid; i < c2; i += 1024) atomicAdd(&scur[score_bin(cb[OFF2 + i].x)], 1u);
    if (RL >= 3) for (u32 i = tid; i < c3; i += 1024) atomicAdd(&scur[score_bin(cb[OFF3 + i].x)], 1u);
    if (RL >= 4) for (u32 i = tid; i < c4; i += 1024) atomicAdd(&scur[score_bin(cb[OFF4 + i].x)], 1u);
  } else {
    for (int P = tid; P < NPAIR; P += 1024) {
      u32 b0, b1, gi0, gi1;
      score_pair(P, b, p2, p3, p4, p5, b0, b1, gi0, gi1);
      if (b0) atomicAdd(&scur[score_bin(b0)], 1u);
      if (b1) atomicAdd(&scur[score_bin(b1)], 1u);
    }
  }
  __syncthreads();

  // ---- wave-0 shfl suffix scan + min-reduce cutoff
  if (tid < 64) {
    u32 h[64];
    #pragma unroll
    for (int k = 0; k < 64; ++k) h[k] = scur[tid * 64 + k];
    u32 lsum = 0;
    #pragma unroll
    for (int k = 0; k < 64; ++k) lsum += h[k];
    u32 S = lsum;
    #pragma unroll
    for (int off = 1; off < 64; off <<= 1) {
      u32 v = (u32)__shfl_down((int)S, off, 64);
      if (tid + off < 64) S += v;
    }
    u32 c = S - lsum;                           // cnt_ge(64*tid + 64)
    int Bv = -1; u32 nv = 0;
    for (int k = 63; k >= 0; --k) {
      sstart[tid * 64 + k] = c;                 // cnt_ge(bin+1)
      c += h[k];                                // cnt_ge(bin)
      if (c <= (u32)KTOP) { Bv = tid * 64 + k; nv = c; }
    }
    u32 pk = (Bv < 0) ? 0xFFFFFFFFu : (((u32)Bv << 12) | nv);
    #pragma unroll
    for (int off = 32; off >= 1; off >>= 1) {
      u32 o = (u32)__shfl_down((int)pk, off, 64);
      if (tid + off < 64) pk = min(pk, o);
    }
    if (tid == 0) {
      if (pk == 0xFFFFFFFFu) { s_B = 4095; s_n = KTOP; }
      else { s_B = max((int)(pk >> 12), 1); s_n = (int)(pk & 0xFFFu); }
    }
  }
  __syncthreads();
  const int B = s_B;
  const int n = min(s_n, KTOP);

  for (int i = tid; i < NBIN; i += 1024) scur[i] = sstart[i];
  __syncthreads();

  // ---- scatter survivors (bin >= B) into counting slots
  if (!fb) {
    for (u32 i = tid; i < c0; i += 1024) {
      uint2 e = cb[OFF0 + i]; int bin = score_bin(e.x);
      if (bin >= B) { u32 sl = atomicAdd(&scur[bin], 1u);
        if (sl < (u32)KTOP) skey[sl] = ((u64)e.x << 32) | (u32)(~e.y); }
    }
    if (RL >= 1) for (u32 i = tid; i < c1; i += 1024) {
      uint2 e = cb[OFF1 + i]; int bin = score_bin(e.x);
      if (bin >= B) { u32 sl = atomicAdd(&scur[bin], 1u);
        if (sl < (u32)KTOP) skey[sl] = ((u64)e.x << 32) | (u32)(~e.y); }
    }
    if (RL >= 2) for (u32 i = tid; i < c2; i += 1024) {
      uint2 e = cb[OFF2 + i]; int bin = score_bin(e.x);
      if (bin >= B) { u32 sl = atomicAdd(&scur[bin], 1u);
        if (sl < (u32)KTOP) skey[sl] = ((u64)e.x << 32) | (u32)(~e.y); }
    }
    if (RL >= 3) for (u32 i = tid; i < c3; i += 1024) {
      uint2 e = cb[OFF3 + i]; int bin = score_bin(e.x);
      if (bin >= B) { u32 sl = atomicAdd(&scur[bin], 1u);
        if (sl < (u32)KTOP) skey[sl] = ((u64)e.x << 32) | (u32)(~e.y); }
    }
    if (RL >= 4) for (u32 i = tid; i < c4; i += 1024) {
      uint2 e = cb[OFF4 + i]; int bin = score_bin(e.x);
      if (bin >= B) { u32 sl = atomicAdd(&scur[bin], 1u);
        if (sl < (u32)KTOP) skey[sl] = ((u64)e.x << 32) | (u32)(~e.y); }
    }
  } else {
    for (int P = tid; P < NPAIR; P += 1024) {
      u32 b0, b1, gi0, gi1;
      score_pair(P, b, p2, p3, p4, p5, b0, b1, gi0, gi1);
      if (b0) { int bin = score_bin(b0);
        if (bin >= B) { u32 sl = atomicAdd(&scur[bin], 1u);
          if (sl < (u32)KTOP) skey[sl] = ((u64)b0 << 32) | (u32)(~gi0); } }
      if (b1) { int bin = score_bin(b1);
        if (bin >= B) { u32 sl = atomicAdd(&scur[bin], 1u);
          if (sl < (u32)KTOP) skey[sl] = ((u64)b1 << 32) | (u32)(~gi1); } }
    }
  }
  __syncthreads();

  // ---- exact rank sort within bins (barrier-free)
  for (int s = tid; s < n; s += 1024) {
    u64 k = skey[s];
    int bin = score_bin((u32)(k >> 32));
    int st = (int)sstart[bin];
    int en = (int)scur[bin];
    u32 r = 0;
    for (int j = st; j < en; ++j) r += (skey[j] > k) ? 1u : 0u;
    skey2[st + r] = k;
  }
  __syncthreads();

  const int Wn = min(n, WIN);

  // ---- window boxes
  if (tid < WIN) {
    sbox[tid] = (tid < Wn) ? decode_box_from_gidx(~(u32)skey2[tid], b, p2, p3, p4, p5)
                           : make_float4(0.f, 0.f, 0.f, 0.f);
  }
  __syncthreads();

  // ---- IoU bitmask matrix; row = tid&255, word = tid>>8 (broadcast reads)
  {
    int row = tid & 255, word = tid >> 8;
    u64 bits = 0;
    if (row < Wn) {
      float4 A = sbox[row];
      int j0 = word * 64;
      int je = min(64, Wn - j0);
      for (int j = 0; j < je; ++j)
        if (iou_gt(A, sbox[j0 + j])) bits |= (1ull << j);
    }
    smat[word * 256 + row] = bits;
  }
  __syncthreads();

  // ---- greedy selection on wave 0, matrix rows in registers
  if (tid < 64) {
    const int lane = tid;
    u64 m0[4], m1[4], m2[4], m3[4];
    #pragma unroll
    for (int w = 0; w < 4; ++w) {
      m0[w] = smat[w * 256 +   0 + lane];
      m1[w] = smat[w * 256 +  64 + lane];
      m2[w] = smat[w * 256 + 128 + lane];
      m3[w] = smat[w * 256 + 192 + lane];
    }
    u64 live[4];
    #pragma unroll
    for (int g2 = 0; g2 < 4; ++g2) {
      int lo = g2 * 64;
      live[g2] = (Wn >= lo + 64) ? ~0ull : (Wn > lo ? ((1ull << (Wn - lo)) - 1ull) : 0ull);
    }
    int sel = 0;
    #pragma unroll 1
    for (int w2 = 0; w2 < 4; ++w2) {
      while (live[w2] && sel < 100) {
        int j = (int)__ffsll(live[w2]) - 1;
        int p = (w2 << 6) + j;
        u64 r0, r1, r2, r3;
        if (w2 == 0)      { r0 = shfl_u64(m0[0], j); r1 = shfl_u64(m0[1], j); r2 = shfl_u64(m0[2], j); r3 = shfl_u64(m0[3], j); }
        else if (w2 == 1) { r0 = shfl_u64(m1[0], j); r1 = shfl_u64(m1[1], j); r2 = shfl_u64(m1[2], j); r3 = shfl_u64(m1[3], j); }
        else if (w2 == 2) { r0 = shfl_u64(m2[0], j); r1 = shfl_u64(m2[1], j); r2 = shfl_u64(m2[2], j); r3 = shfl_u64(m2[3], j); }
        else              { r0 = shfl_u64(m3[0], j); r1 = shfl_u64(m3[1], j); r2 = shfl_u64(m3[2], j); r3 = shfl_u64(m3[3], j); }
        live[0] &= ~r0; live[1] &= ~r1; live[2] &= ~r2; live[3] &= ~r3;
        live[w2] &= ~(1ull << j);
        if (lane == 0) {
          float4 box = sbox[p];
          u64 k = skey2[p];
          float sc = __uint_as_float((u32)(k >> 32));
          selbox[sel] = box;
          float* orow = out + (size_t)b * 500 + (size_t)sel * 5;
          orow[0] = box.x; orow[1] = box.y; orow[2] = box.z; orow[3] = box.w; orow[4] = sc;
        }
        sel++;
      }
    }
    if (lane == 0) {
      s_misc[2] = sel;
      s_misc[3] = (sel < 100 && n > WIN) ? 1 : 0;
    }
  }
  __syncthreads();

  // ---- exact slow path beyond the window (statistically never taken)
  if (s_misc[3]) {
    if (tid < 64) {
      const int lane = tid;
      int sel = s_misc[2];
      for (int p = WIN; p < n && sel < 100; ++p) {
        u64 k = skey2[p];
        float4 box = decode_box_from_gidx(~(u32)k, b, p2, p3, p4, p5);
        bool hit = false;
        if (lane < sel) hit = iou_gt(selbox[lane], box);
        if (lane + 64 < sel) hit = hit || iou_gt(selbox[lane + 64], box);
        u64 anyhit = __ballot(hit);
        if (anyhit == 0ull) {
          if (lane == 0) {
            selbox[sel] = box;
            float sc = __uint_as_float((u32)(k >> 32));
            float* orow = out + (size_t)b * 500 + (size_t)sel * 5;
            orow[0] = box.x; orow[1] = box.y; orow[2] = box.z; orow[3] = box.w; orow[4] = sc;
          }
          sel++;
        }
      }
      if (lane == 0) s_misc[2] = sel;
    }
  }
  __syncthreads();

  // ---- zero-fill remaining rows
  const int nsel = s_misc[2];
  for (int i = tid; i < (100 - nsel) * 5; i += 1024)
    out[(size_t)b * 500 + (size_t)nsel * 5 + i] = 0.0f;
  __syncthreads();

  // ---- signal heaters
  if (tid == 0) atomicAdd(&counters[DONE_SLOT], 1u);
}

// ---------------------------------------------------------------- launch
extern "C" void kernel_launch(void* const* d_in, const int* in_sizes, int n_in,
                              void* d_out, int out_size, void* d_ws, size_t ws_size,
                              hipStream_t stream) {
  const float* p2 = (const float*)d_in[0];
  const float* p3 = (const float*)d_in[1];
  const float* p4 = (const float*)d_in[2];
  const float* p5 = (const float*)d_in[3];
  float* out = (float*)d_out;

  unsigned char* w = (unsigned char*)d_ws;
  u32*   counters = (u32*)w;
  uint2* cand     = (uint2*)(w + WS_CAND);

  hipMemsetAsync(counters, 0, 32 * CSTRIDE * sizeof(u32), stream);
  decode_kernel<<<dim3(120, 32), 512, 0, stream>>>(p2, p3, p4, p5, counters, cand);
  mega_kernel<<<256, 1024, 0, stream>>>(counters, cand, p2, p3, p4, p5, out);
}

// Round 11
// 173.466 us; speedup vs baseline: 1.0661x; 1.0661x over previous
//
#include <hip/hip_runtime.h>
#include <cstdint>
#include <cstddef>

typedef unsigned int u32;
typedef unsigned long long u64;

#define NTOT 122740      // total proposals (records) per batch
#define NPAIR 61370
#define KTOP 1024        // top-K kept per batch (deterministic bin-cutoff set)
#define WIN  256         // IoU-matrix window over the sorted list
#define NBIN 4096
#define SCORE_T 0.25f
#define TBITS 0x3E800000u       // bit pattern of 0.25f

// range thresholds on score bits (bin boundaries 3584/3072/2560/2048)
#define RT0 0x3F5DF000u   // bin >= 3584
#define RT1 0x3F3FF000u   // bin >= 3072
#define RT2 0x3F1FF000u   // bin >= 2560
#define RT3 0x3EFFF000u   // bin >= 2048

#define CSTRIDE 128             // counters per batch (u32); counter r at r*16 (64B apart)
// per-batch range capacities and offsets (entries)
#define CAP0 4096
#define CAP1 8192
#define CAP2 12288
#define CAP3 16384
#define CAP4 16384
#define OFF0 0
#define OFF1 4096
#define OFF2 12288
#define OFF3 24576
#define OFF4 40960
#define BATCH_ENT 57344

// concatenated float4 layout per batch (all level boundaries are f4-aligned):
//   L2: f4 [0,      138624)  p2, batch stride 138624 f4
//   L3: f4 [138624, 173280)  p3, stride 34656
//   L4: f4 [173280, 181944)  p4, stride 8664
//   L5: f4 [181944, 184110)  p5, stride 2166
#define F4TOT 184110
#define F4B3 138624
#define F4B4 173280
#define F4B5 181944

#define F4_PER_BLK 3072         // f4 per decode block (2048 records)

// ws layout (bytes):
//   counters: 32*128*4        = 16384     @ 0
//   cand:     32*57344*8      = 14680064  @ 16384   (~14.7 MB total)
#define WS_CAND 16384

// ---------------------------------------------------------------- helpers
__device__ __forceinline__ float sigm(float x) { return 1.0f / (1.0f + expf(-x)); }

__device__ __forceinline__ int score_bin(u32 bits) {
  return min(4095, 1 + (int)((bits - TBITS) >> 12));
}

__device__ __forceinline__ u64 shfl_u64(u64 x, int src) {
  int lo = __shfl((int)(u32)x, src, 64);
  int hi = __shfl((int)(u32)(x >> 32), src, 64);
  return ((u64)(u32)hi << 32) | (u32)lo;
}

// fallback-only: scores for record pair P (records 2P, 2P+1) of batch b
__device__ __forceinline__ void score_pair(int P, int b,
    const float* __restrict__ p2, const float* __restrict__ p3,
    const float* __restrict__ p4, const float* __restrict__ p5,
    u32& b0, u32& b1, u32& gi0, u32& gi1)
{
  int t0 = 2 * P;
  const float* p; int l0, LN;
  if (t0 < 92416)       { p = p2; l0 = t0;          LN = 92416; }
  else if (t0 < 115520) { p = p3; l0 = t0 - 92416;  LN = 23104; }
  else if (t0 < 121296) { p = p4; l0 = t0 - 115520; LN = 5776;  }
  else                  { p = p5; l0 = t0 - 121296; LN = 1444;  }
  const float* q = p + ((size_t)b * LN + (size_t)l0) * 6;
  float4 v1 = *(const float4*)(q + 4);
  float4 v2 = *(const float4*)(q + 8);
  float s0 = sigm(v1.x) * sigm(v1.y);
  float s1 = sigm(v2.z) * sigm(v2.w);
  b0 = (s0 >= SCORE_T) ? __float_as_uint(s0) : 0u;
  b1 = (s1 >= SCORE_T) ? __float_as_uint(s1) : 0u;
  gi0 = (u32)t0; gi1 = (u32)(t0 + 1);
}

__device__ float4 decode_box_from_gidx(u32 gidx, int b,
    const float* __restrict__ p2, const float* __restrict__ p3,
    const float* __restrict__ p4, const float* __restrict__ p5)
{
  const float* p; int t, H, W; float stride;
  float aw0, ah0, aw1, ah1, aw2, ah2, aw3, ah3;
  if (gidx < 92416u) {
    p = p2 + (size_t)b * 92416 * 6; t = (int)gidx; H = 152; W = 152; stride = 4.0f;
    aw0=12.f; ah0=16.f; aw1=19.f; ah1=36.f; aw2=40.f; ah2=28.f; aw3=36.f; ah3=75.f;
  } else if (gidx < 115520u) {
    p = p3 + (size_t)b * 23104 * 6; t = (int)(gidx - 92416u); H = 76; W = 76; stride = 8.0f;
    aw0=36.f; ah0=75.f; aw1=76.f; ah1=55.f; aw2=72.f; ah2=146.f; aw3=142.f; ah3=110.f;
  } else if (gidx < 121296u) {
    p = p4 + (size_t)b * 5776 * 6; t = (int)(gidx - 115520u); H = 38; W = 38; stride = 16.0f;
    aw0=72.f; ah0=146.f; aw1=142.f; ah1=110.f; aw2=192.f; ah2=243.f; aw3=459.f; ah3=401.f;
  } else {
    p = p5 + (size_t)b * 1444 * 6; t = (int)(gidx - 121296u); H = 19; W = 19; stride = 32.0f;
    aw0=142.f; ah0=110.f; aw1=192.f; ah1=243.f; aw2=300.f; ah2=300.f; aw3=459.f; ah3=401.f;
  }
  int HW = H * W;
  int a = t / HW;
  int r = t - a * HW;
  int y = r / W;
  int x = r - y * W;
  const float* q = p + (size_t)t * 6;
  float2 t01 = *(const float2*)(q + 0);
  float2 t23 = *(const float2*)(q + 2);
  float cx = (sigm(t01.x) + (float)x) * stride;
  float cy = (sigm(t01.y) + (float)y) * stride;
  float aw = (a == 0) ? aw0 : (a == 1) ? aw1 : (a == 2) ? aw2 : aw3;
  float ah = (a == 0) ? ah0 : (a == 1) ? ah1 : (a == 2) ? ah2 : ah3;
  float bw = expf(t23.x) * aw;
  float bh = expf(t23.y) * ah;
  return make_float4(cx - 0.5f * bw, cy - 0.5f * bh, cx + 0.5f * bw, cy + 0.5f * bh);
}

__device__ __forceinline__ bool iou_gt(float4 A, float4 B) {
  float ltx = fmaxf(A.x, B.x), lty = fmaxf(A.y, B.y);
  float rbx = fminf(A.z, B.z), rby = fminf(A.w, B.w);
  float w = fmaxf(rbx - ltx, 0.0f), h = fmaxf(rby - lty, 0.0f);
  float inter = w * h;
  float a1 = fmaxf(A.z - A.x, 0.0f) * fmaxf(A.w - A.y, 0.0f);
  float a2 = fmaxf(B.z - B.x, 0.0f) * fmaxf(B.w - B.y, 0.0f);
  float iou = inter / (a1 + a2 - inter + 1e-9f);
  return iou > 0.5f;
}

// ---------------------------------------------------------------- A: decode, zero-staging
// grid (60, 32), 512 thr, 3072 f4 (2048 records) per block. Dense f4 loads; for every
// record, conf/cls always lie within ONE f4 (offset (6r+4)%4 in {0,2}):
//   i%3==1 -> record 2*(i/3) conf/cls = v.xy ; i%3==2 -> record 2*(i/3)+1 = v.zw.
// Survivors partitioned into 5 range segments in LDS, one global atomic per range.
__global__ __launch_bounds__(512)
void decode_kernel(const float* __restrict__ p2, const float* __restrict__ p3,
                   const float* __restrict__ p4, const float* __restrict__ p5,
                   u32* __restrict__ counters, uint2* __restrict__ cand)
{
  __shared__ uint2 stg[2048];             // 16 KB worst-case all survive
  __shared__ u32 lcnt[8], lseg[8], lrank[8], gbase[8];
  const int tid = threadIdx.x;
  const int b = blockIdx.y;
  if (tid < 8) { lcnt[tid] = 0u; lrank[tid] = 0u; gbase[tid] = 0u; }
  __syncthreads();

  const float4* q2 = (const float4*)p2;
  const float4* q3 = (const float4*)p3;
  const float4* q4 = (const float4*)p4;
  const float4* q5 = (const float4*)p5;
  const int FS = blockIdx.x * F4_PER_BLK;

  u32 kb[6]; u32 kg6[6]; int kr6[6];
  #pragma unroll
  for (int k = 0; k < 6; ++k) {
    kb[k] = 0u; kr6[k] = -1; kg6[k] = 0u;
    int i4 = FS + k * 512 + tid;
    if (i4 < F4TOT) {
      const float4* src;
      if (i4 < F4B3)      src = q2 + (size_t)b * 138624 + i4;
      else if (i4 < F4B4) src = q3 + (size_t)b * 34656  + (i4 - F4B3);
      else if (i4 < F4B5) src = q4 + (size_t)b * 8664   + (i4 - F4B4);
      else                src = q5 + (size_t)b * 2166   + (i4 - F4B5);
      float4 v = *src;
      int k3 = i4 / 3;
      int trib = i4 - 3 * k3;
      if (trib) {
        float cf = (trib == 1) ? v.x : v.z;
        float cl = (trib == 1) ? v.y : v.w;
        float s = sigm(cf) * sigm(cl);
        if (s >= SCORE_T) {
          u32 bb = __float_as_uint(s);
          int r;
          if      (bb >= RT0) r = 0;
          else if (bb >= RT1) r = 1;
          else if (bb >= RT2) r = 2;
          else if (bb >= RT3) r = 3;
          else                r = 4;
          kb[k] = bb; kr6[k] = r;
          kg6[k] = (u32)(2 * k3 + (trib - 1));
          atomicAdd(&lcnt[r], 1u);
        }
      }
    }
  }
  __syncthreads();
  if (tid == 0) {
    u32 s = 0;
    #pragma unroll
    for (int r = 0; r < 5; ++r) { lseg[r] = s; s += lcnt[r]; }
  }
  if (tid < 5 && lcnt[tid]) gbase[tid] = atomicAdd(&counters[(size_t)b * CSTRIDE + tid * 16], lcnt[tid]);
  __syncthreads();
  #pragma unroll
  for (int k = 0; k < 6; ++k) {
    if (kr6[k] >= 0) {
      u32 rk = atomicAdd(&lrank[kr6[k]], 1u);
      stg[lseg[kr6[k]] + rk] = make_uint2(kb[k], kg6[k]);
    }
  }
  __syncthreads();
  uint2* cb = cand + (size_t)b * BATCH_ENT;
  const u32 roff[5] = { OFF0, OFF1, OFF2, OFF3, OFF4 };
  const u32 rcap[5] = { CAP0, CAP1, CAP2, CAP3, CAP4 };
  #pragma unroll
  for (int r = 0; r < 5; ++r) {
    const u32 cnt = lcnt[r], sg = lseg[r], gb = gbase[r];
    for (u32 i = tid; i < cnt; i += 512) {
      u32 d = gb + i;
      if (d < rcap[r]) cb[roff[r] + d] = stg[sg + i];
    }
  }
}

// ---------------------------------------------------------------- M: range-pruned backend
// One block per batch: hist -> conflict-free multi-wave suffix scan -> counting
// scatter -> exact in-bin rank sort -> window IoU -> register greedy NMS.
__global__ __launch_bounds__(1024, 1)
void mega_kernel(const u32* __restrict__ counters, const uint2* __restrict__ cand,
                 const float* __restrict__ p2, const float* __restrict__ p3,
                 const float* __restrict__ p4, const float* __restrict__ p5,
                 float* __restrict__ out)
{
  const int b = blockIdx.x;
  const int tid = threadIdx.x;
  const int lane = tid & 63, wv = tid >> 6;

  __shared__ __align__(16) u32 sstart[NBIN];  // 16 KB  cnt_ge(bin+1)
  __shared__ __align__(16) u32 scur[NBIN];    // 16 KB  hist, then cursors
  __shared__ u32 wred[16];                    // wave totals / min-reduce scratch
  __shared__ u64 skey[KTOP];                  // 8 KB
  __shared__ u64 skey2[KTOP];                 // 8 KB
  __shared__ float4 sbox[WIN];                // 4 KB
  __shared__ u64 smat[WIN * 4];               // 8 KB
  __shared__ float4 selbox[100];              // 1.6 KB
  __shared__ int s_misc[4];
  __shared__ int s_B, s_n;

  const u32 c0 = counters[(size_t)b * CSTRIDE +  0];
  const u32 c1 = counters[(size_t)b * CSTRIDE + 16];
  const u32 c2 = counters[(size_t)b * CSTRIDE + 32];
  const u32 c3 = counters[(size_t)b * CSTRIDE + 48];
  const u32 c4 = counters[(size_t)b * CSTRIDE + 64];
  const u32 total = c0 + c1 + c2 + c3 + c4;
  const u32 need = min((u32)KTOP, total);
  int RL = 0;
  { u32 cum = c0;
    if (cum < need) { RL = 1; cum += c1; }
    if (cum < need) { RL = 2; cum += c2; }
    if (cum < need) { RL = 3; cum += c3; }
    if (cum < need) { RL = 4; cum += c4; }
  }
  const bool fb = (c0 > (u32)CAP0)
               || (RL >= 1 && c1 > (u32)CAP1)
               || (RL >= 2 && c2 > (u32)CAP2)
               || (RL >= 3 && c3 > (u32)CAP3)
               || (RL >= 4 && c4 > (u32)CAP4);

  ((uint4*)scur)[tid] = make_uint4(0u, 0u, 0u, 0u);
  __syncthreads();

  const uint2* cb = cand + (size_t)b * BATCH_ENT;

  // ---- hist (ranges 0..RL)
  if (!fb) {
    for (u32 i = tid; i < c0; i += 1024) atomicAdd(&scur[score_bin(cb[OFF0 + i].x)], 1u);
    if (RL >= 1) for (u32 i = tid; i < c1; i += 1024) atomicAdd(&scur[score_bin(cb[OFF1 + i].x)], 1u);
    if (RL >= 2) for (u32 i = tid; i < c2; i += 1024) atomicAdd(&scur[score_bin(cb[OFF2 + i].x)], 1u);
    if (RL >= 3) for (u32 i = tid; i < c3; i += 1024) atomicAdd(&scur[score_bin(cb[OFF3 + i].x)], 1u);
    if (RL >= 4) for (u32 i = tid; i < c4; i += 1024) atomicAdd(&scur[score_bin(cb[OFF4 + i].x)], 1u);
  } else {
    for (int P = tid; P < NPAIR; P += 1024) {
      u32 b0, b1, gi0, gi1;
      score_pair(P, b, p2, p3, p4, p5, b0, b1, gi0, gi1);
      if (b0) atomicAdd(&scur[score_bin(b0)], 1u);
      if (b1) atomicAdd(&scur[score_bin(b1)], 1u);
    }
  }
  __syncthreads();

  // ---- conflict-free multi-wave suffix scan (thread t owns bins [4t,4t+4))
  {
    uint4 hv = ((const uint4*)scur)[tid];              // b128, conflict-free
    u32 loc4[4] = { hv.x, hv.y, hv.z, hv.w };
    u32 lsum = hv.x + hv.y + hv.z + hv.w;
    // within-wave inclusive suffix scan
    u32 S = lsum;
    #pragma unroll
    for (int off = 1; off < 64; off <<= 1) {
      u32 v = (u32)__shfl_down((int)S, off, 64);
      if (lane + off < 64) S += v;
    }
    u32 wtot = (u32)__shfl((int)S, 0, 64);
    if (lane == 0) wred[wv] = wtot;
    __syncthreads();
    u32 U = 0;
    for (int w2 = wv + 1; w2 < 16; ++w2) U += wred[w2]; // suffix-excl over waves
    u32 T = U + (S - lsum);                              // cnt_ge(4t+4)
    u32 ss[4];
    u32 run = T;
    #pragma unroll
    for (int j = 3; j >= 0; --j) { ss[j] = run; run += loc4[j]; }
    ((uint4*)sstart)[tid] = make_uint4(ss[0], ss[1], ss[2], ss[3]);
    // cutoff candidate: smallest bin in [4t,4t+4) with cnt_ge(bin) <= KTOP
    u32 pk = 0xFFFFFFFFu;
    #pragma unroll
    for (int j = 0; j < 4; ++j) {
      u32 cge = ss[j] + loc4[j];
      if (pk == 0xFFFFFFFFu && cge <= (u32)KTOP) pk = ((u32)(4 * tid + j) << 12) | cge;
    }
    #pragma unroll
    for (int off = 32; off >= 1; off >>= 1) {
      u32 o = (u32)__shfl_down((int)pk, off, 64);
      if (lane + off < 64) pk = min(pk, o);
    }
    __syncthreads();                                     // wred reuse
    if (lane == 0) wred[wv] = pk;
    __syncthreads();
    if (tid == 0) {
      u32 m = 0xFFFFFFFFu;
      for (int w2 = 0; w2 < 16; ++w2) m = min(m, wred[w2]);
      if (m == 0xFFFFFFFFu) { s_B = 4095; s_n = KTOP; }  // unreachable
      else { s_B = max((int)(m >> 12), 1); s_n = (int)(m & 0xFFFu); }
    }
  }
  __syncthreads();
  const int B = s_B;
  const int n = min(s_n, KTOP);

  ((uint4*)scur)[tid] = ((const uint4*)sstart)[tid];     // cursors
  __syncthreads();

  // ---- scatter survivors (bin >= B) into counting slots
  if (!fb) {
    for (u32 i = tid; i < c0; i += 1024) {
      uint2 e = cb[OFF0 + i]; int bin = score_bin(e.x);
      if (bin >= B) { u32 sl = atomicAdd(&scur[bin], 1u);
        if (sl < (u32)KTOP) skey[sl] = ((u64)e.x << 32) | (u32)(~e.y); }
    }
    if (RL >= 1) for (u32 i = tid; i < c1; i += 1024) {
      uint2 e = cb[OFF1 + i]; int bin = score_bin(e.x);
      if (bin >= B) { u32 sl = atomicAdd(&scur[bin], 1u);
        if (sl < (u32)KTOP) skey[sl] = ((u64)e.x << 32) | (u32)(~e.y); }
    }
    if (RL >= 2) for (u32 i = tid; i < c2; i += 1024) {
      uint2 e = cb[OFF2 + i]; int bin = score_bin(e.x);
      if (bin >= B) { u32 sl = atomicAdd(&scur[bin], 1u);
        if (sl < (u32)KTOP) skey[sl] = ((u64)e.x << 32) | (u32)(~e.y); }
    }
    if (RL >= 3) for (u32 i = tid; i < c3; i += 1024) {
      uint2 e = cb[OFF3 + i]; int bin = score_bin(e.x);
      if (bin >= B) { u32 sl = atomicAdd(&scur[bin], 1u);
        if (sl < (u32)KTOP) skey[sl] = ((u64)e.x << 32) | (u32)(~e.y); }
    }
    if (RL >= 4) for (u32 i = tid; i < c4; i += 1024) {
      uint2 e = cb[OFF4 + i]; int bin = score_bin(e.x);
      if (bin >= B) { u32 sl = atomicAdd(&scur[bin], 1u);
        if (sl < (u32)KTOP) skey[sl] = ((u64)e.x << 32) | (u32)(~e.y); }
    }
  } else {
    for (int P = tid; P < NPAIR; P += 1024) {
      u32 b0, b1, gi0, gi1;
      score_pair(P, b, p2, p3, p4, p5, b0, b1, gi0, gi1);
      if (b0) { int bin = score_bin(b0);
        if (bin >= B) { u32 sl = atomicAdd(&scur[bin], 1u);
          if (sl < (u32)KTOP) skey[sl] = ((u64)b0 << 32) | (u32)(~gi0); } }
      if (b1) { int bin = score_bin(b1);
        if (bin >= B) { u32 sl = atomicAdd(&scur[bin], 1u);
          if (sl < (u32)KTOP) skey[sl] = ((u64)b1 << 32) | (u32)(~gi1); } }
    }
  }
  __syncthreads();

  // ---- exact rank sort within bins (barrier-free)
  for (int s = tid; s < n; s += 1024) {
    u64 k = skey[s];
    int bin = score_bin((u32)(k >> 32));
    int st = (int)sstart[bin];
    int en = (int)scur[bin];
    u32 r = 0;
    for (int j = st; j < en; ++j) r += (skey[j] > k) ? 1u : 0u;
    skey2[st + r] = k;
  }
  __syncthreads();

  const int Wn = min(n, WIN);

  // ---- window boxes
  if (tid < WIN) {
    sbox[tid] = (tid < Wn) ? decode_box_from_gidx(~(u32)skey2[tid], b, p2, p3, p4, p5)
                           : make_float4(0.f, 0.f, 0.f, 0.f);
  }
  __syncthreads();

  // ---- IoU bitmask matrix; row = tid&255, word = tid>>8 (broadcast reads)
  {
    int row = tid & 255, word = tid >> 8;
    u64 bits = 0;
    if (row < Wn) {
      float4 A = sbox[row];
      int j0 = word * 64;
      int je = min(64, Wn - j0);
      for (int j = 0; j < je; ++j)
        if (iou_gt(A, sbox[j0 + j])) bits |= (1ull << j);
    }
    smat[word * 256 + row] = bits;
  }
  __syncthreads();

  // ---- greedy selection on wave 0, matrix rows in registers
  if (tid < 64) {
    u64 m0[4], m1[4], m2[4], m3[4];
    #pragma unroll
    for (int w = 0; w < 4; ++w) {
      m0[w] = smat[w * 256 +   0 + lane];
      m1[w] = smat[w * 256 +  64 + lane];
      m2[w] = smat[w * 256 + 128 + lane];
      m3[w] = smat[w * 256 + 192 + lane];
    }
    u64 live[4];
    #pragma unroll
    for (int g2 = 0; g2 < 4; ++g2) {
      int lo = g2 * 64;
      live[g2] = (Wn >= lo + 64) ? ~0ull : (Wn > lo ? ((1ull << (Wn - lo)) - 1ull) : 0ull);
    }
    int sel = 0;
    #pragma unroll 1
    for (int w2 = 0; w2 < 4; ++w2) {
      while (live[w2] && sel < 100) {
        int j = (int)__ffsll(live[w2]) - 1;
        int p = (w2 << 6) + j;
        u64 r0, r1, r2, r3;
        if (w2 == 0)      { r0 = shfl_u64(m0[0], j); r1 = shfl_u64(m0[1], j); r2 = shfl_u64(m0[2], j); r3 = shfl_u64(m0[3], j); }
        else if (w2 == 1) { r0 = shfl_u64(m1[0], j); r1 = shfl_u64(m1[1], j); r2 = shfl_u64(m1[2], j); r3 = shfl_u64(m1[3], j); }
        else if (w2 == 2) { r0 = shfl_u64(m2[0], j); r1 = shfl_u64(m2[1], j); r2 = shfl_u64(m2[2], j); r3 = shfl_u64(m2[3], j); }
        else              { r0 = shfl_u64(m3[0], j); r1 = shfl_u64(m3[1], j); r2 = shfl_u64(m3[2], j); r3 = shfl_u64(m3[3], j); }
        live[0] &= ~r0; live[1] &= ~r1; live[2] &= ~r2; live[3] &= ~r3;
        live[w2] &= ~(1ull << j);
        if (lane == 0) {
          float4 box = sbox[p];
          u64 k = skey2[p];
          float sc = __uint_as_float((u32)(k >> 32));
          selbox[sel] = box;
          float* orow = out + (size_t)b * 500 + (size_t)sel * 5;
          orow[0] = box.x; orow[1] = box.y; orow[2] = box.z; orow[3] = box.w; orow[4] = sc;
        }
        sel++;
      }
    }
    if (lane == 0) {
      s_misc[2] = sel;
      s_misc[3] = (sel < 100 && n > WIN) ? 1 : 0;
    }
  }
  __syncthreads();

  // ---- exact slow path beyond the window (statistically never taken)
  if (s_misc[3]) {
    if (tid < 64) {
      int sel = s_misc[2];
      for (int p = WIN; p < n && sel < 100; ++p) {
        u64 k = skey2[p];
        float4 box = decode_box_from_gidx(~(u32)k, b, p2, p3, p4, p5);
        bool hit = false;
        if (lane < sel) hit = iou_gt(selbox[lane], box);
        if (lane + 64 < sel) hit = hit || iou_gt(selbox[lane + 64], box);
        u64 anyhit = __ballot(hit);
        if (anyhit == 0ull) {
          if (lane == 0) {
            selbox[sel] = box;
            float sc = __uint_as_float((u32)(k >> 32));
            float* orow = out + (size_t)b * 500 + (size_t)sel * 5;
            orow[0] = box.x; orow[1] = box.y; orow[2] = box.z; orow[3] = box.w; orow[4] = sc;
          }
          sel++;
        }
      }
      if (lane == 0) s_misc[2] = sel;
    }
  }
  __syncthreads();

  // ---- zero-fill remaining rows
  const int nsel = s_misc[2];
  for (int i = tid; i < (100 - nsel) * 5; i += 1024)
    out[(size_t)b * 500 + (size_t)nsel * 5 + i] = 0.0f;
}

// ---------------------------------------------------------------- launch
extern "C" void kernel_launch(void* const* d_in, const int* in_sizes, int n_in,
                              void* d_out, int out_size, void* d_ws, size_t ws_size,
                              hipStream_t stream) {
  const float* p2 = (const float*)d_in[0];
  const float* p3 = (const float*)d_in[1];
  const float* p4 = (const float*)d_in[2];
  const float* p5 = (const float*)d_in[3];
  float* out = (float*)d_out;

  unsigned char* w = (unsigned char*)d_ws;
  u32*   counters = (u32*)w;
  uint2* cand     = (uint2*)(w + WS_CAND);

  hipMemsetAsync(counters, 0, 32 * CSTRIDE * sizeof(u32), stream);
  decode_kernel<<<dim3(60, 32), 512, 0, stream>>>(p2, p3, p4, p5, counters, cand);
  mega_kernel<<<32, 1024, 0, stream>>>(counters, cand, p2, p3, p4, p5, out);
}

// Round 12
// 161.270 us; speedup vs baseline: 1.1467x; 1.0756x over previous
//
#include <hip/hip_runtime.h>
#include <cstdint>
#include <cstddef>

typedef unsigned int u32;
typedef unsigned long long u64;

#define NTOT 122740      // total proposals (records) per batch
#define NPAIR 61370
#define KTOP 1024        // top-K kept per batch (deterministic bin-cutoff set)
#define WIN  256         // IoU-matrix window over the sorted list
#define NBIN 4096
#define SCORE_T 0.25f
#define TBITS 0x3E800000u       // bit pattern of 0.25f

// range thresholds on score bits (bin boundaries 3584/3072/2560/2048)
#define RT0 0x3F5DF000u   // bin >= 3584
#define RT1 0x3F3FF000u   // bin >= 3072
#define RT2 0x3F1FF000u   // bin >= 2560
#define RT3 0x3EFFF000u   // bin >= 2048

#define CSTRIDE 128             // counters per batch (u32); counter r at r*16 (64B apart)
// per-batch range capacities and offsets (entries)
#define CAP0 4096
#define CAP1 8192
#define CAP2 12288
#define CAP3 16384
#define CAP4 16384
#define OFF0 0
#define OFF1 4096
#define OFF2 12288
#define OFF3 24576
#define OFF4 40960
#define BATCH_ENT 57344

// concatenated float4 layout per batch (all level boundaries are f4-aligned):
//   L2: f4 [0,      138624)  p2, batch stride 138624 f4
//   L3: f4 [138624, 173280)  p3, stride 34656
//   L4: f4 [173280, 181944)  p4, stride 8664
//   L5: f4 [181944, 184110)  p5, stride 2166
#define F4TOT 184110
#define F4B3 138624
#define F4B4 173280
#define F4B5 181944

#define F4_PER_BLK 3072         // f4 per decode block (2048 records)

// ws layout (bytes):
//   counters: 32*128*4        = 16384     @ 0
//   cand:     32*57344*8      = 14680064  @ 16384   (~14.7 MB total)
#define WS_CAND 16384

// ---------------------------------------------------------------- helpers
__device__ __forceinline__ float sigm(float x) { return 1.0f / (1.0f + expf(-x)); }

__device__ __forceinline__ int score_bin(u32 bits) {
  return min(4095, 1 + (int)((bits - TBITS) >> 12));
}

__device__ __forceinline__ u64 shfl_u64(u64 x, int src) {
  int lo = __shfl((int)(u32)x, src, 64);
  int hi = __shfl((int)(u32)(x >> 32), src, 64);
  return ((u64)(u32)hi << 32) | (u32)lo;
}

// fallback-only: scores for record pair P (records 2P, 2P+1) of batch b
__device__ __forceinline__ void score_pair(int P, int b,
    const float* __restrict__ p2, const float* __restrict__ p3,
    const float* __restrict__ p4, const float* __restrict__ p5,
    u32& b0, u32& b1, u32& gi0, u32& gi1)
{
  int t0 = 2 * P;
  const float* p; int l0, LN;
  if (t0 < 92416)       { p = p2; l0 = t0;          LN = 92416; }
  else if (t0 < 115520) { p = p3; l0 = t0 - 92416;  LN = 23104; }
  else if (t0 < 121296) { p = p4; l0 = t0 - 115520; LN = 5776;  }
  else                  { p = p5; l0 = t0 - 121296; LN = 1444;  }
  const float* q = p + ((size_t)b * LN + (size_t)l0) * 6;
  float4 v1 = *(const float4*)(q + 4);
  float4 v2 = *(const float4*)(q + 8);
  float s0 = sigm(v1.x) * sigm(v1.y);
  float s1 = sigm(v2.z) * sigm(v2.w);
  b0 = (s0 >= SCORE_T) ? __float_as_uint(s0) : 0u;
  b1 = (s1 >= SCORE_T) ? __float_as_uint(s1) : 0u;
  gi0 = (u32)t0; gi1 = (u32)(t0 + 1);
}

__device__ float4 decode_box_from_gidx(u32 gidx, int b,
    const float* __restrict__ p2, const float* __restrict__ p3,
    const float* __restrict__ p4, const float* __restrict__ p5)
{
  const float* p; int t, H, W; float stride;
  float aw0, ah0, aw1, ah1, aw2, ah2, aw3, ah3;
  if (gidx < 92416u) {
    p = p2 + (size_t)b * 92416 * 6; t = (int)gidx; H = 152; W = 152; stride = 4.0f;
    aw0=12.f; ah0=16.f; aw1=19.f; ah1=36.f; aw2=40.f; ah2=28.f; aw3=36.f; ah3=75.f;
  } else if (gidx < 115520u) {
    p = p3 + (size_t)b * 23104 * 6; t = (int)(gidx - 92416u); H = 76; W = 76; stride = 8.0f;
    aw0=36.f; ah0=75.f; aw1=76.f; ah1=55.f; aw2=72.f; ah2=146.f; aw3=142.f; ah3=110.f;
  } else if (gidx < 121296u) {
    p = p4 + (size_t)b * 5776 * 6; t = (int)(gidx - 115520u); H = 38; W = 38; stride = 16.0f;
    aw0=72.f; ah0=146.f; aw1=142.f; ah1=110.f; aw2=192.f; ah2=243.f; aw3=459.f; ah3=401.f;
  } else {
    p = p5 + (size_t)b * 1444 * 6; t = (int)(gidx - 121296u); H = 19; W = 19; stride = 32.0f;
    aw0=142.f; ah0=110.f; aw1=192.f; ah1=243.f; aw2=300.f; ah2=300.f; aw3=459.f; ah3=401.f;
  }
  int HW = H * W;
  int a = t / HW;
  int r = t - a * HW;
  int y = r / W;
  int x = r - y * W;
  const float* q = p + (size_t)t * 6;
  float2 t01 = *(const float2*)(q + 0);
  float2 t23 = *(const float2*)(q + 2);
  float cx = (sigm(t01.x) + (float)x) * stride;
  float cy = (sigm(t01.y) + (float)y) * stride;
  float aw = (a == 0) ? aw0 : (a == 1) ? aw1 : (a == 2) ? aw2 : aw3;
  float ah = (a == 0) ? ah0 : (a == 1) ? ah1 : (a == 2) ? ah2 : ah3;
  float bw = expf(t23.x) * aw;
  float bh = expf(t23.y) * ah;
  return make_float4(cx - 0.5f * bw, cy - 0.5f * bh, cx + 0.5f * bw, cy + 0.5f * bh);
}

__device__ __forceinline__ bool iou_gt(float4 A, float4 B) {
  float ltx = fmaxf(A.x, B.x), lty = fmaxf(A.y, B.y);
  float rbx = fminf(A.z, B.z), rby = fminf(A.w, B.w);
  float w = fmaxf(rbx - ltx, 0.0f), h = fmaxf(rby - lty, 0.0f);
  float inter = w * h;
  float a1 = fmaxf(A.z - A.x, 0.0f) * fmaxf(A.w - A.y, 0.0f);
  float a2 = fmaxf(B.z - B.x, 0.0f) * fmaxf(B.w - B.y, 0.0f);
  float iou = inter / (a1 + a2 - inter + 1e-9f);
  return iou > 0.5f;
}

// ---------------------------------------------------------------- A: decode, zero-staging (unchanged)
__global__ __launch_bounds__(512)
void decode_kernel(const float* __restrict__ p2, const float* __restrict__ p3,
                   const float* __restrict__ p4, const float* __restrict__ p5,
                   u32* __restrict__ counters, uint2* __restrict__ cand)
{
  __shared__ uint2 stg[2048];             // 16 KB worst-case all survive
  __shared__ u32 lcnt[8], lseg[8], lrank[8], gbase[8];
  const int tid = threadIdx.x;
  const int b = blockIdx.y;
  if (tid < 8) { lcnt[tid] = 0u; lrank[tid] = 0u; gbase[tid] = 0u; }
  __syncthreads();

  const float4* q2 = (const float4*)p2;
  const float4* q3 = (const float4*)p3;
  const float4* q4 = (const float4*)p4;
  const float4* q5 = (const float4*)p5;
  const int FS = blockIdx.x * F4_PER_BLK;

  u32 kb[6]; u32 kg6[6]; int kr6[6];
  #pragma unroll
  for (int k = 0; k < 6; ++k) {
    kb[k] = 0u; kr6[k] = -1; kg6[k] = 0u;
    int i4 = FS + k * 512 + tid;
    if (i4 < F4TOT) {
      const float4* src;
      if (i4 < F4B3)      src = q2 + (size_t)b * 138624 + i4;
      else if (i4 < F4B4) src = q3 + (size_t)b * 34656  + (i4 - F4B3);
      else if (i4 < F4B5) src = q4 + (size_t)b * 8664   + (i4 - F4B4);
      else                src = q5 + (size_t)b * 2166   + (i4 - F4B5);
      float4 v = *src;
      int k3 = i4 / 3;
      int trib = i4 - 3 * k3;
      if (trib) {
        float cf = (trib == 1) ? v.x : v.z;
        float cl = (trib == 1) ? v.y : v.w;
        float s = sigm(cf) * sigm(cl);
        if (s >= SCORE_T) {
          u32 bb = __float_as_uint(s);
          int r;
          if      (bb >= RT0) r = 0;
          else if (bb >= RT1) r = 1;
          else if (bb >= RT2) r = 2;
          else if (bb >= RT3) r = 3;
          else                r = 4;
          kb[k] = bb; kr6[k] = r;
          kg6[k] = (u32)(2 * k3 + (trib - 1));
          atomicAdd(&lcnt[r], 1u);
        }
      }
    }
  }
  __syncthreads();
  if (tid == 0) {
    u32 s = 0;
    #pragma unroll
    for (int r = 0; r < 5; ++r) { lseg[r] = s; s += lcnt[r]; }
  }
  if (tid < 5 && lcnt[tid]) gbase[tid] = atomicAdd(&counters[(size_t)b * CSTRIDE + tid * 16], lcnt[tid]);
  __syncthreads();
  #pragma unroll
  for (int k = 0; k < 6; ++k) {
    if (kr6[k] >= 0) {
      u32 rk = atomicAdd(&lrank[kr6[k]], 1u);
      stg[lseg[kr6[k]] + rk] = make_uint2(kb[k], kg6[k]);
    }
  }
  __syncthreads();
  uint2* cb = cand + (size_t)b * BATCH_ENT;
  const u32 roff[5] = { OFF0, OFF1, OFF2, OFF3, OFF4 };
  const u32 rcap[5] = { CAP0, CAP1, CAP2, CAP3, CAP4 };
  #pragma unroll
  for (int r = 0; r < 5; ++r) {
    const u32 cnt = lcnt[r], sg = lseg[r], gb = gbase[r];
    for (u32 i = tid; i < cnt; i += 512) {
      u32 d = gb + i;
      if (d < rcap[r]) cb[roff[r] + d] = stg[sg + i];
    }
  }
}

// ---------------------------------------------------------------- M: range-pruned backend
// greedy rewritten: ALL-STATIC register state (16 named u64 rows, 4 named live
// words, manually unrolled word loops -> no runtime-indexed arrays -> no scratch
// spill), deferred output (lane 0 records index only; writes done in parallel after)
__global__ __launch_bounds__(1024, 1)
void mega_kernel(const u32* __restrict__ counters, const uint2* __restrict__ cand,
                 const float* __restrict__ p2, const float* __restrict__ p3,
                 const float* __restrict__ p4, const float* __restrict__ p5,
                 float* __restrict__ out)
{
  const int b = blockIdx.x;
  const int tid = threadIdx.x;
  const int lane = tid & 63, wv = tid >> 6;

  __shared__ __align__(16) u32 sstart[NBIN];  // 16 KB  cnt_ge(bin+1)
  __shared__ __align__(16) u32 scur[NBIN];    // 16 KB  hist, then cursors
  __shared__ u32 wred[16];                    // wave totals / min-reduce scratch
  __shared__ u64 skey[KTOP];                  // 8 KB
  __shared__ u64 skey2[KTOP];                 // 8 KB
  __shared__ float4 sbox[WIN];                // 4 KB
  __shared__ u64 smat[WIN * 4];               // 8 KB  [word][row]
  __shared__ float4 selbox[100];              // 1.6 KB
  __shared__ u32 s_sellist[100];
  __shared__ int s_misc[4];
  __shared__ int s_B, s_n;

  const u32 c0 = counters[(size_t)b * CSTRIDE +  0];
  const u32 c1 = counters[(size_t)b * CSTRIDE + 16];
  const u32 c2 = counters[(size_t)b * CSTRIDE + 32];
  const u32 c3 = counters[(size_t)b * CSTRIDE + 48];
  const u32 c4 = counters[(size_t)b * CSTRIDE + 64];
  const u32 total = c0 + c1 + c2 + c3 + c4;
  const u32 need = min((u32)KTOP, total);
  int RL = 0;
  { u32 cum = c0;
    if (cum < need) { RL = 1; cum += c1; }
    if (cum < need) { RL = 2; cum += c2; }
    if (cum < need) { RL = 3; cum += c3; }
    if (cum < need) { RL = 4; cum += c4; }
  }
  const bool fb = (c0 > (u32)CAP0)
               || (RL >= 1 && c1 > (u32)CAP1)
               || (RL >= 2 && c2 > (u32)CAP2)
               || (RL >= 3 && c3 > (u32)CAP3)
               || (RL >= 4 && c4 > (u32)CAP4);

  ((uint4*)scur)[tid] = make_uint4(0u, 0u, 0u, 0u);
  __syncthreads();

  const uint2* cb = cand + (size_t)b * BATCH_ENT;

  // ---- hist (ranges 0..RL)
  if (!fb) {
    for (u32 i = tid; i < c0; i += 1024) atomicAdd(&scur[score_bin(cb[OFF0 + i].x)], 1u);
    if (RL >= 1) for (u32 i = tid; i < c1; i += 1024) atomicAdd(&scur[score_bin(cb[OFF1 + i].x)], 1u);
    if (RL >= 2) for (u32 i = tid; i < c2; i += 1024) atomicAdd(&scur[score_bin(cb[OFF2 + i].x)], 1u);
    if (RL >= 3) for (u32 i = tid; i < c3; i += 1024) atomicAdd(&scur[score_bin(cb[OFF3 + i].x)], 1u);
    if (RL >= 4) for (u32 i = tid; i < c4; i += 1024) atomicAdd(&scur[score_bin(cb[OFF4 + i].x)], 1u);
  } else {
    for (int P = tid; P < NPAIR; P += 1024) {
      u32 b0, b1, gi0, gi1;
      score_pair(P, b, p2, p3, p4, p5, b0, b1, gi0, gi1);
      if (b0) atomicAdd(&scur[score_bin(b0)], 1u);
      if (b1) atomicAdd(&scur[score_bin(b1)], 1u);
    }
  }
  __syncthreads();

  // ---- conflict-free multi-wave suffix scan (thread t owns bins [4t,4t+4))
  {
    uint4 hv = ((const uint4*)scur)[tid];              // b128, conflict-free
    u32 loc4[4] = { hv.x, hv.y, hv.z, hv.w };
    u32 lsum = hv.x + hv.y + hv.z + hv.w;
    u32 S = lsum;
    #pragma unroll
    for (int off = 1; off < 64; off <<= 1) {
      u32 v = (u32)__shfl_down((int)S, off, 64);
      if (lane + off < 64) S += v;
    }
    u32 wtot = (u32)__shfl((int)S, 0, 64);
    if (lane == 0) wred[wv] = wtot;
    __syncthreads();
    u32 U = 0;
    for (int w2 = wv + 1; w2 < 16; ++w2) U += wred[w2]; // suffix-excl over waves
    u32 T = U + (S - lsum);                              // cnt_ge(4t+4)
    u32 ss[4];
    u32 run = T;
    #pragma unroll
    for (int j = 3; j >= 0; --j) { ss[j] = run; run += loc4[j]; }
    ((uint4*)sstart)[tid] = make_uint4(ss[0], ss[1], ss[2], ss[3]);
    u32 pk = 0xFFFFFFFFu;
    #pragma unroll
    for (int j = 0; j < 4; ++j) {
      u32 cge = ss[j] + loc4[j];
      if (pk == 0xFFFFFFFFu && cge <= (u32)KTOP) pk = ((u32)(4 * tid + j) << 12) | cge;
    }
    #pragma unroll
    for (int off = 32; off >= 1; off >>= 1) {
      u32 o = (u32)__shfl_down((int)pk, off, 64);
      if (lane + off < 64) pk = min(pk, o);
    }
    __syncthreads();                                     // wred reuse
    if (lane == 0) wred[wv] = pk;
    __syncthreads();
    if (tid == 0) {
      u32 m = 0xFFFFFFFFu;
      for (int w2 = 0; w2 < 16; ++w2) m = min(m, wred[w2]);
      if (m == 0xFFFFFFFFu) { s_B = 4095; s_n = KTOP; }  // unreachable
      else { s_B = max((int)(m >> 12), 1); s_n = (int)(m & 0xFFFu); }
    }
  }
  __syncthreads();
  const int B = s_B;
  const int n = min(s_n, KTOP);

  ((uint4*)scur)[tid] = ((const uint4*)sstart)[tid];     // cursors
  __syncthreads();

  // ---- scatter survivors (bin >= B) into counting slots
  if (!fb) {
    for (u32 i = tid; i < c0; i += 1024) {
      uint2 e = cb[OFF0 + i]; int bin = score_bin(e.x);
      if (bin >= B) { u32 sl = atomicAdd(&scur[bin], 1u);
        if (sl < (u32)KTOP) skey[sl] = ((u64)e.x << 32) | (u32)(~e.y); }
    }
    if (RL >= 1) for (u32 i = tid; i < c1; i += 1024) {
      uint2 e = cb[OFF1 + i]; int bin = score_bin(e.x);
      if (bin >= B) { u32 sl = atomicAdd(&scur[bin], 1u);
        if (sl < (u32)KTOP) skey[sl] = ((u64)e.x << 32) | (u32)(~e.y); }
    }
    if (RL >= 2) for (u32 i = tid; i < c2; i += 1024) {
      uint2 e = cb[OFF2 + i]; int bin = score_bin(e.x);
      if (bin >= B) { u32 sl = atomicAdd(&scur[bin], 1u);
        if (sl < (u32)KTOP) skey[sl] = ((u64)e.x << 32) | (u32)(~e.y); }
    }
    if (RL >= 3) for (u32 i = tid; i < c3; i += 1024) {
      uint2 e = cb[OFF3 + i]; int bin = score_bin(e.x);
      if (bin >= B) { u32 sl = atomicAdd(&scur[bin], 1u);
        if (sl < (u32)KTOP) skey[sl] = ((u64)e.x << 32) | (u32)(~e.y); }
    }
    if (RL >= 4) for (u32 i = tid; i < c4; i += 1024) {
      uint2 e = cb[OFF4 + i]; int bin = score_bin(e.x);
      if (bin >= B) { u32 sl = atomicAdd(&scur[bin], 1u);
        if (sl < (u32)KTOP) skey[sl] = ((u64)e.x << 32) | (u32)(~e.y); }
    }
  } else {
    for (int P = tid; P < NPAIR; P += 1024) {
      u32 b0, b1, gi0, gi1;
      score_pair(P, b, p2, p3, p4, p5, b0, b1, gi0, gi1);
      if (b0) { int bin = score_bin(b0);
        if (bin >= B) { u32 sl = atomicAdd(&scur[bin], 1u);
          if (sl < (u32)KTOP) skey[sl] = ((u64)b0 << 32) | (u32)(~gi0); } }
      if (b1) { int bin = score_bin(b1);
        if (bin >= B) { u32 sl = atomicAdd(&scur[bin], 1u);
          if (sl < (u32)KTOP) skey[sl] = ((u64)b1 << 32) | (u32)(~gi1); } }
    }
  }
  __syncthreads();

  // ---- exact rank sort within bins (barrier-free)
  for (int s = tid; s < n; s += 1024) {
    u64 k = skey[s];
    int bin = score_bin((u32)(k >> 32));
    int st = (int)sstart[bin];
    int en = (int)scur[bin];
    u32 r = 0;
    for (int j = st; j < en; ++j) r += (skey[j] > k) ? 1u : 0u;
    skey2[st + r] = k;
  }
  __syncthreads();

  const int Wn = min(n, WIN);

  // ---- window boxes
  if (tid < WIN) {
    sbox[tid] = (tid < Wn) ? decode_box_from_gidx(~(u32)skey2[tid], b, p2, p3, p4, p5)
                           : make_float4(0.f, 0.f, 0.f, 0.f);
  }
  __syncthreads();

  // ---- IoU bitmask matrix; row = tid&255, word = tid>>8 (broadcast reads)
  {
    int row = tid & 255, word = tid >> 8;
    u64 bits = 0;
    if (row < Wn) {
      float4 A = sbox[row];
      int j0 = word * 64;
      int je = min(64, Wn - j0);
      for (int j = 0; j < je; ++j)
        if (iou_gt(A, sbox[j0 + j])) bits |= (1ull << j);
    }
    smat[word * 256 + row] = bits;
  }
  __syncthreads();

  // ---- greedy selection on wave 0: all-static register state, deferred writes
  if (tid < 64) {
    // named row scalars: mXw = word w of row (X*64 + lane)
    u64 mA0 = smat[0*256 +   0 + lane], mA1 = smat[1*256 +   0 + lane],
        mA2 = smat[2*256 +   0 + lane], mA3 = smat[3*256 +   0 + lane];
    u64 mB0 = smat[0*256 +  64 + lane], mB1 = smat[1*256 +  64 + lane],
        mB2 = smat[2*256 +  64 + lane], mB3 = smat[3*256 +  64 + lane];
    u64 mC0 = smat[0*256 + 128 + lane], mC1 = smat[1*256 + 128 + lane],
        mC2 = smat[2*256 + 128 + lane], mC3 = smat[3*256 + 128 + lane];
    u64 mD0 = smat[0*256 + 192 + lane], mD1 = smat[1*256 + 192 + lane],
        mD2 = smat[2*256 + 192 + lane], mD3 = smat[3*256 + 192 + lane];

    u64 live0 = (Wn >=  64) ? ~0ull : (Wn >   0 ? ((1ull << (Wn -   0)) - 1ull) : 0ull);
    u64 live1 = (Wn >= 128) ? ~0ull : (Wn >  64 ? ((1ull << (Wn -  64)) - 1ull) : 0ull);
    u64 live2 = (Wn >= 192) ? ~0ull : (Wn > 128 ? ((1ull << (Wn - 128)) - 1ull) : 0ull);
    u64 live3 = (Wn >= 256) ? ~0ull : (Wn > 192 ? ((1ull << (Wn - 192)) - 1ull) : 0ull);
    int sel = 0;

    while (live0 && sel < 100) {                      // word group 0
      int j = (int)__ffsll(live0) - 1;
      u64 r0 = shfl_u64(mA0, j), r1 = shfl_u64(mA1, j),
          r2 = shfl_u64(mA2, j), r3 = shfl_u64(mA3, j);
      live0 &= ~r0; live1 &= ~r1; live2 &= ~r2; live3 &= ~r3;
      live0 &= ~(1ull << j);
      if (lane == 0) s_sellist[sel] = (u32)j;
      sel++;
    }
    while (live1 && sel < 100) {                      // word group 1
      int j = (int)__ffsll(live1) - 1;
      u64 r0 = shfl_u64(mB0, j), r1 = shfl_u64(mB1, j),
          r2 = shfl_u64(mB2, j), r3 = shfl_u64(mB3, j);
      live0 &= ~r0; live1 &= ~r1; live2 &= ~r2; live3 &= ~r3;
      live1 &= ~(1ull << j);
      if (lane == 0) s_sellist[sel] = (u32)(64 + j);
      sel++;
    }
    while (live2 && sel < 100) {                      // word group 2
      int j = (int)__ffsll(live2) - 1;
      u64 r0 = shfl_u64(mC0, j), r1 = shfl_u64(mC1, j),
          r2 = shfl_u64(mC2, j), r3 = shfl_u64(mC3, j);
      live0 &= ~r0; live1 &= ~r1; live2 &= ~r2; live3 &= ~r3;
      live2 &= ~(1ull << j);
      if (lane == 0) s_sellist[sel] = (u32)(128 + j);
      sel++;
    }
    while (live3 && sel < 100) {                      // word group 3
      int j = (int)__ffsll(live3) - 1;
      u64 r0 = shfl_u64(mD0, j), r1 = shfl_u64(mD1, j),
          r2 = shfl_u64(mD2, j), r3 = shfl_u64(mD3, j);
      live0 &= ~r0; live1 &= ~r1; live2 &= ~r2; live3 &= ~r3;
      live3 &= ~(1ull << j);
      if (lane == 0) s_sellist[sel] = (u32)(192 + j);
      sel++;
    }
    if (lane == 0) {
      s_misc[2] = sel;
      s_misc[3] = (sel < 100 && n > WIN) ? 1 : 0;
    }
  }
  __syncthreads();

  // ---- parallel deferred write of selected boxes
  {
    const int nsel0 = s_misc[2];
    if (tid < nsel0) {
      int p = (int)s_sellist[tid];
      u64 k = skey2[p];
      float4 box = sbox[p];
      selbox[tid] = box;
      float* orow = out + (size_t)b * 500 + (size_t)tid * 5;
      orow[0] = box.x; orow[1] = box.y; orow[2] = box.z; orow[3] = box.w;
      orow[4] = __uint_as_float((u32)(k >> 32));
    }
  }
  __syncthreads();

  // ---- exact slow path beyond the window (statistically never taken)
  if (s_misc[3]) {
    if (tid < 64) {
      int sel = s_misc[2];
      for (int p = WIN; p < n && sel < 100; ++p) {
        u64 k = skey2[p];
        float4 box = decode_box_from_gidx(~(u32)k, b, p2, p3, p4, p5);
        bool hit = false;
        if (lane < sel) hit = iou_gt(selbox[lane], box);
        if (lane + 64 < sel) hit = hit || iou_gt(selbox[lane + 64], box);
        u64 anyhit = __ballot(hit);
        if (anyhit == 0ull) {
          if (lane == 0) {
            selbox[sel] = box;
            float sc = __uint_as_float((u32)(k >> 32));
            float* orow = out + (size_t)b * 500 + (size_t)sel * 5;
            orow[0] = box.x; orow[1] = box.y; orow[2] = box.z; orow[3] = box.w; orow[4] = sc;
          }
          sel++;
        }
      }
      if (lane == 0) s_misc[2] = sel;
    }
  }
  __syncthreads();

  // ---- zero-fill remaining rows
  const int nsel = s_misc[2];
  for (int i = tid; i < (100 - nsel) * 5; i += 1024)
    out[(size_t)b * 500 + (size_t)nsel * 5 + i] = 0.0f;
}

// ---------------------------------------------------------------- launch
extern "C" void kernel_launch(void* const* d_in, const int* in_sizes, int n_in,
                              void* d_out, int out_size, void* d_ws, size_t ws_size,
                              hipStream_t stream) {
  const float* p2 = (const float*)d_in[0];
  const float* p3 = (const float*)d_in[1];
  const float* p4 = (const float*)d_in[2];
  const float* p5 = (const float*)d_in[3];
  float* out = (float*)d_out;

  unsigned char* w = (unsigned char*)d_ws;
  u32*   counters = (u32*)w;
  uint2* cand     = (uint2*)(w + WS_CAND);

  hipMemsetAsync(counters, 0, 32 * CSTRIDE * sizeof(u32), stream);
  decode_kernel<<<dim3(60, 32), 512, 0, stream>>>(p2, p3, p4, p5, counters, cand);
  mega_kernel<<<32, 1024, 0, stream>>>(counters, cand, p2, p3, p4, p5, out);
}

// Round 13
// 160.048 us; speedup vs baseline: 1.1554x; 1.0076x over previous
//
#include <hip/hip_runtime.h>
#include <cstdint>
#include <cstddef>

typedef unsigned int u32;
typedef unsigned long long u64;

#define NTOT 122740      // total proposals (records) per batch
#define NPAIR 61370
#define KTOP 1024        // top-K kept per batch (deterministic bin-cutoff set)
#define WIN  256         // IoU-matrix window over the sorted list
#define NBIN 4096
#define SCORE_T 0.25f
#define TBITS 0x3E800000u       // bit pattern of 0.25f

// range thresholds on score bits (bin boundaries 3584/3072/2560/2048)
#define RT0 0x3F5DF000u   // bin >= 3584
#define RT1 0x3F3FF000u   // bin >= 3072
#define RT2 0x3F1FF000u   // bin >= 2560
#define RT3 0x3EFFF000u   // bin >= 2048

// ---- legacy (atomic-append) path layout
#define CSTRIDE 128
#define CAP0 4096
#define CAP1 8192
#define CAP2 12288
#define CAP3 16384
#define CAP4 16384
#define OFF0 0
#define OFF1 4096
#define OFF2 12288
#define OFF3 24576
#define OFF4 40960
#define BATCH_ENT 57344
#define WS_CAND_OLD 16384

// ---- deterministic-region path layout
#define NREG 60                 // decode blocks per batch == regions
#define REG_ENT 2048            // records per region (overflow impossible)
#define CNT_PAD 8               // count-table row padding (u32)
#define WS_CANDDET 65536
// need = 65536 + 32*60*2048*8
#define NEED_DET 31522816ull

// concatenated float4 layout per batch (all level boundaries are f4-aligned)
#define F4TOT 184110
#define F4B3 138624
#define F4B4 173280
#define F4B5 181944
#define F4_PER_BLK 3072         // f4 per decode block (2048 records)

// ---------------------------------------------------------------- helpers
__device__ __forceinline__ float sigm(float x) { return 1.0f / (1.0f + expf(-x)); }

__device__ __forceinline__ int score_bin(u32 bits) {
  return min(4095, 1 + (int)((bits - TBITS) >> 12));
}

__device__ __forceinline__ u64 shfl_u64(u64 x, int src) {
  int lo = __shfl((int)(u32)x, src, 64);
  int hi = __shfl((int)(u32)(x >> 32), src, 64);
  return ((u64)(u32)hi << 32) | (u32)lo;
}

// legacy-fallback-only: scores for record pair P of batch b
__device__ __forceinline__ void score_pair(int P, int b,
    const float* __restrict__ p2, const float* __restrict__ p3,
    const float* __restrict__ p4, const float* __restrict__ p5,
    u32& b0, u32& b1, u32& gi0, u32& gi1)
{
  int t0 = 2 * P;
  const float* p; int l0, LN;
  if (t0 < 92416)       { p = p2; l0 = t0;          LN = 92416; }
  else if (t0 < 115520) { p = p3; l0 = t0 - 92416;  LN = 23104; }
  else if (t0 < 121296) { p = p4; l0 = t0 - 115520; LN = 5776;  }
  else                  { p = p5; l0 = t0 - 121296; LN = 1444;  }
  const float* q = p + ((size_t)b * LN + (size_t)l0) * 6;
  float4 v1 = *(const float4*)(q + 4);
  float4 v2 = *(const float4*)(q + 8);
  float s0 = sigm(v1.x) * sigm(v1.y);
  float s1 = sigm(v2.z) * sigm(v2.w);
  b0 = (s0 >= SCORE_T) ? __float_as_uint(s0) : 0u;
  b1 = (s1 >= SCORE_T) ? __float_as_uint(s1) : 0u;
  gi0 = (u32)t0; gi1 = (u32)(t0 + 1);
}

__device__ float4 decode_box_from_gidx(u32 gidx, int b,
    const float* __restrict__ p2, const float* __restrict__ p3,
    const float* __restrict__ p4, const float* __restrict__ p5)
{
  const float* p; int t, H, W; float stride;
  float aw0, ah0, aw1, ah1, aw2, ah2, aw3, ah3;
  if (gidx < 92416u) {
    p = p2 + (size_t)b * 92416 * 6; t = (int)gidx; H = 152; W = 152; stride = 4.0f;
    aw0=12.f; ah0=16.f; aw1=19.f; ah1=36.f; aw2=40.f; ah2=28.f; aw3=36.f; ah3=75.f;
  } else if (gidx < 115520u) {
    p = p3 + (size_t)b * 23104 * 6; t = (int)(gidx - 92416u); H = 76; W = 76; stride = 8.0f;
    aw0=36.f; ah0=75.f; aw1=76.f; ah1=55.f; aw2=72.f; ah2=146.f; aw3=142.f; ah3=110.f;
  } else if (gidx < 121296u) {
    p = p4 + (size_t)b * 5776 * 6; t = (int)(gidx - 115520u); H = 38; W = 38; stride = 16.0f;
    aw0=72.f; ah0=146.f; aw1=142.f; ah1=110.f; aw2=192.f; ah2=243.f; aw3=459.f; ah3=401.f;
  } else {
    p = p5 + (size_t)b * 1444 * 6; t = (int)(gidx - 121296u); H = 19; W = 19; stride = 32.0f;
    aw0=142.f; ah0=110.f; aw1=192.f; ah1=243.f; aw2=300.f; ah2=300.f; aw3=459.f; ah3=401.f;
  }
  int HW = H * W;
  int a = t / HW;
  int r = t - a * HW;
  int y = r / W;
  int x = r - y * W;
  const float* q = p + (size_t)t * 6;
  float2 t01 = *(const float2*)(q + 0);
  float2 t23 = *(const float2*)(q + 2);
  float cx = (sigm(t01.x) + (float)x) * stride;
  float cy = (sigm(t01.y) + (float)y) * stride;
  float aw = (a == 0) ? aw0 : (a == 1) ? aw1 : (a == 2) ? aw2 : aw3;
  float ah = (a == 0) ? ah0 : (a == 1) ? ah1 : (a == 2) ? ah2 : ah3;
  float bw = expf(t23.x) * aw;
  float bh = expf(t23.y) * ah;
  return make_float4(cx - 0.5f * bw, cy - 0.5f * bh, cx + 0.5f * bw, cy + 0.5f * bh);
}

__device__ __forceinline__ bool iou_gt(float4 A, float4 B) {
  float ltx = fmaxf(A.x, B.x), lty = fmaxf(A.y, B.y);
  float rbx = fminf(A.z, B.z), rby = fminf(A.w, B.w);
  float w = fmaxf(rbx - ltx, 0.0f), h = fmaxf(rby - lty, 0.0f);
  float inter = w * h;
  float a1 = fmaxf(A.z - A.x, 0.0f) * fmaxf(A.w - A.y, 0.0f);
  float a2 = fmaxf(B.z - B.x, 0.0f) * fmaxf(B.w - B.y, 0.0f);
  float iou = inter / (a1 + a2 - inter + 1e-9f);
  return iou > 0.5f;
}

// ---------------------------------------------------------------- A: decode, zero-staging
// grid (60, 32), 512 thr, 2048 records/block. det=1: deterministic region write
// (no global atomics, no memset needed). det=0: legacy atomic append.
__global__ __launch_bounds__(512)
void decode_kernel(const float* __restrict__ p2, const float* __restrict__ p3,
                   const float* __restrict__ p4, const float* __restrict__ p5,
                   u32* __restrict__ counters, uint2* __restrict__ cand_old,
                   u32* __restrict__ cnttab, uint2* __restrict__ cand_det,
                   int det)
{
  __shared__ uint2 stg[2048];             // 16 KB worst-case all survive
  __shared__ u32 lcnt[8], lseg[8], lrank[8], gbase[8];
  const int tid = threadIdx.x;
  const int b = blockIdx.y;
  if (tid < 8) { lcnt[tid] = 0u; lrank[tid] = 0u; gbase[tid] = 0u; }
  __syncthreads();

  const float4* q2 = (const float4*)p2;
  const float4* q3 = (const float4*)p3;
  const float4* q4 = (const float4*)p4;
  const float4* q5 = (const float4*)p5;
  const int FS = blockIdx.x * F4_PER_BLK;

  u32 kb[6]; u32 kg6[6]; int kr6[6];
  #pragma unroll
  for (int k = 0; k < 6; ++k) {
    kb[k] = 0u; kr6[k] = -1; kg6[k] = 0u;
    int i4 = FS + k * 512 + tid;
    if (i4 < F4TOT) {
      const float4* src;
      if (i4 < F4B3)      src = q2 + (size_t)b * 138624 + i4;
      else if (i4 < F4B4) src = q3 + (size_t)b * 34656  + (i4 - F4B3);
      else if (i4 < F4B5) src = q4 + (size_t)b * 8664   + (i4 - F4B4);
      else                src = q5 + (size_t)b * 2166   + (i4 - F4B5);
      float4 v = *src;
      int k3 = i4 / 3;
      int trib = i4 - 3 * k3;
      if (trib) {
        float cf = (trib == 1) ? v.x : v.z;
        float cl = (trib == 1) ? v.y : v.w;
        float s = sigm(cf) * sigm(cl);
        if (s >= SCORE_T) {
          u32 bb = __float_as_uint(s);
          int r;
          if      (bb >= RT0) r = 0;
          else if (bb >= RT1) r = 1;
          else if (bb >= RT2) r = 2;
          else if (bb >= RT3) r = 3;
          else                r = 4;
          kb[k] = bb; kr6[k] = r;
          kg6[k] = (u32)(2 * k3 + (trib - 1));
          atomicAdd(&lcnt[r], 1u);
        }
      }
    }
  }
  __syncthreads();
  if (tid == 0) {
    u32 s = 0;
    #pragma unroll
    for (int r = 0; r < 5; ++r) { lseg[r] = s; s += lcnt[r]; }
  }
  if (!det && tid < 5 && lcnt[tid])
    gbase[tid] = atomicAdd(&counters[(size_t)b * CSTRIDE + tid * 16], lcnt[tid]);
  __syncthreads();
  #pragma unroll
  for (int k = 0; k < 6; ++k) {
    if (kr6[k] >= 0) {
      u32 rk = atomicAdd(&lrank[kr6[k]], 1u);
      stg[lseg[kr6[k]] + rk] = make_uint2(kb[k], kg6[k]);
    }
  }
  __syncthreads();

  if (det) {
    if (tid < 5) cnttab[((size_t)b * NREG + blockIdx.x) * CNT_PAD + tid] = lcnt[tid];
    const u32 tot = lseg[4] + lcnt[4];
    uint2* cb = cand_det + ((size_t)b * NREG + blockIdx.x) * REG_ENT;
    for (u32 i = tid; i < tot; i += 512) cb[i] = stg[i];
  } else {
    uint2* cb = cand_old + (size_t)b * BATCH_ENT;
    const u32 roff[5] = { OFF0, OFF1, OFF2, OFF3, OFF4 };
    const u32 rcap[5] = { CAP0, CAP1, CAP2, CAP3, CAP4 };
    #pragma unroll
    for (int r = 0; r < 5; ++r) {
      const u32 cnt = lcnt[r], sg = lseg[r], gb = gbase[r];
      for (u32 i = tid; i < cnt; i += 512) {
        u32 d = gb + i;
        if (d < rcap[r]) cb[roff[r] + d] = stg[sg + i];
      }
    }
  }
}

// ---------------------------------------------------------------- M: range-pruned backend
__global__ __launch_bounds__(1024, 1)
void mega_kernel(const u32* __restrict__ counters, const uint2* __restrict__ cand_old,
                 const u32* __restrict__ cnttab, const uint2* __restrict__ cand_det,
                 const float* __restrict__ p2, const float* __restrict__ p3,
                 const float* __restrict__ p4, const float* __restrict__ p5,
                 float* __restrict__ out, int det)
{
  const int b = blockIdx.x;
  const int tid = threadIdx.x;
  const int lane = tid & 63, wv = tid >> 6;

  __shared__ __align__(16) u32 sstart[NBIN];  // 16 KB  cnt_ge(bin+1)
  __shared__ __align__(16) u32 scur[NBIN];    // 16 KB  hist, then cursors
  __shared__ u32 wred[16];
  __shared__ u32 s_plen[NREG + 4];            // det: per-region prefix length
  __shared__ u64 skey[KTOP];                  // 8 KB
  __shared__ u64 skey2[KTOP];                 // 8 KB
  __shared__ float4 sbox[WIN];                // 4 KB
  __shared__ u64 smat[WIN * 4];               // 8 KB  [word][row]
  __shared__ float4 selbox[100];              // 1.6 KB
  __shared__ u32 s_sellist[100];
  __shared__ int s_misc[4];
  __shared__ int s_B, s_n;

  // ---- front-end: zero hist; build read plan
  ((uint4*)scur)[tid] = make_uint4(0u, 0u, 0u, 0u);

  u32 c0, c1, c2, c3, c4; int RL; bool fb = false;
  if (det) {
    if (tid < 64) {
      u32 m0 = 0, m1 = 0, m2 = 0, m3 = 0, m4 = 0;
      if (lane < NREG) {
        const u32* t = cnttab + ((size_t)b * NREG + lane) * CNT_PAD;
        m0 = t[0]; m1 = t[1]; m2 = t[2]; m3 = t[3]; m4 = t[4];
      }
      u32 r0 = m0, r1 = m1, r2 = m2, r3 = m3, r4 = m4;
      #pragma unroll
      for (int off = 32; off >= 1; off >>= 1) {
        r0 += (u32)__shfl_down((int)r0, off, 64);
        r1 += (u32)__shfl_down((int)r1, off, 64);
        r2 += (u32)__shfl_down((int)r2, off, 64);
        r3 += (u32)__shfl_down((int)r3, off, 64);
        r4 += (u32)__shfl_down((int)r4, off, 64);
      }
      u32 t0 = (u32)__shfl((int)r0, 0, 64), t1 = (u32)__shfl((int)r1, 0, 64);
      u32 t2 = (u32)__shfl((int)r2, 0, 64), t3 = (u32)__shfl((int)r3, 0, 64);
      u32 t4 = (u32)__shfl((int)r4, 0, 64);
      u32 total = t0 + t1 + t2 + t3 + t4;
      u32 need = min((u32)KTOP, total);
      int rl = 0; u32 cum = t0;
      if (cum < need) { rl = 1; cum += t1; }
      if (cum < need) { rl = 2; cum += t2; }
      if (cum < need) { rl = 3; cum += t3; }
      if (cum < need) { rl = 4; cum += t4; }
      u32 pl = m0;
      if (rl >= 1) pl += m1;
      if (rl >= 2) pl += m2;
      if (rl >= 3) pl += m3;
      if (rl >= 4) pl += m4;
      if (lane < NREG) s_plen[lane] = pl;
    }
    __syncthreads();
  } else {
    c0 = counters[(size_t)b * CSTRIDE +  0];
    c1 = counters[(size_t)b * CSTRIDE + 16];
    c2 = counters[(size_t)b * CSTRIDE + 32];
    c3 = counters[(size_t)b * CSTRIDE + 48];
    c4 = counters[(size_t)b * CSTRIDE + 64];
    const u32 total = c0 + c1 + c2 + c3 + c4;
    const u32 need = min((u32)KTOP, total);
    RL = 0;
    { u32 cum = c0;
      if (cum < need) { RL = 1; cum += c1; }
      if (cum < need) { RL = 2; cum += c2; }
      if (cum < need) { RL = 3; cum += c3; }
      if (cum < need) { RL = 4; cum += c4; }
    }
    fb = (c0 > (u32)CAP0)
      || (RL >= 1 && c1 > (u32)CAP1)
      || (RL >= 2 && c2 > (u32)CAP2)
      || (RL >= 3 && c3 > (u32)CAP3)
      || (RL >= 4 && c4 > (u32)CAP4);
    __syncthreads();
  }

  const uint2* cb = cand_old + (size_t)b * BATCH_ENT;

  // ---- hist
  if (det) {
    for (int sg = wv; sg < NREG; sg += 16) {
      const u32 len = s_plen[sg];
      const uint2* seg = cand_det + ((size_t)b * NREG + sg) * REG_ENT;
      for (u32 i = lane; i < len; i += 64) atomicAdd(&scur[score_bin(seg[i].x)], 1u);
    }
  } else if (!fb) {
    for (u32 i = tid; i < c0; i += 1024) atomicAdd(&scur[score_bin(cb[OFF0 + i].x)], 1u);
    if (RL >= 1) for (u32 i = tid; i < c1; i += 1024) atomicAdd(&scur[score_bin(cb[OFF1 + i].x)], 1u);
    if (RL >= 2) for (u32 i = tid; i < c2; i += 1024) atomicAdd(&scur[score_bin(cb[OFF2 + i].x)], 1u);
    if (RL >= 3) for (u32 i = tid; i < c3; i += 1024) atomicAdd(&scur[score_bin(cb[OFF3 + i].x)], 1u);
    if (RL >= 4) for (u32 i = tid; i < c4; i += 1024) atomicAdd(&scur[score_bin(cb[OFF4 + i].x)], 1u);
  } else {
    for (int P = tid; P < NPAIR; P += 1024) {
      u32 b0, b1, gi0, gi1;
      score_pair(P, b, p2, p3, p4, p5, b0, b1, gi0, gi1);
      if (b0) atomicAdd(&scur[score_bin(b0)], 1u);
      if (b1) atomicAdd(&scur[score_bin(b1)], 1u);
    }
  }
  __syncthreads();

  // ---- conflict-free multi-wave suffix scan (thread t owns bins [4t,4t+4))
  {
    uint4 hv = ((const uint4*)scur)[tid];
    u32 loc4[4] = { hv.x, hv.y, hv.z, hv.w };
    u32 lsum = hv.x + hv.y + hv.z + hv.w;
    u32 S = lsum;
    #pragma unroll
    for (int off = 1; off < 64; off <<= 1) {
      u32 v = (u32)__shfl_down((int)S, off, 64);
      if (lane + off < 64) S += v;
    }
    u32 wtot = (u32)__shfl((int)S, 0, 64);
    if (lane == 0) wred[wv] = wtot;
    __syncthreads();
    u32 U = 0;
    for (int w2 = wv + 1; w2 < 16; ++w2) U += wred[w2];
    u32 T = U + (S - lsum);                              // cnt_ge(4t+4)
    u32 ss[4];
    u32 run = T;
    #pragma unroll
    for (int j = 3; j >= 0; --j) { ss[j] = run; run += loc4[j]; }
    ((uint4*)sstart)[tid] = make_uint4(ss[0], ss[1], ss[2], ss[3]);
    u32 pk = 0xFFFFFFFFu;
    #pragma unroll
    for (int j = 0; j < 4; ++j) {
      u32 cge = ss[j] + loc4[j];
      if (pk == 0xFFFFFFFFu && cge <= (u32)KTOP) pk = ((u32)(4 * tid + j) << 12) | cge;
    }
    #pragma unroll
    for (int off = 32; off >= 1; off >>= 1) {
      u32 o = (u32)__shfl_down((int)pk, off, 64);
      if (lane + off < 64) pk = min(pk, o);
    }
    __syncthreads();
    if (lane == 0) wred[wv] = pk;
    __syncthreads();
    if (tid == 0) {
      u32 m = 0xFFFFFFFFu;
      for (int w2 = 0; w2 < 16; ++w2) m = min(m, wred[w2]);
      if (m == 0xFFFFFFFFu) { s_B = 4095; s_n = KTOP; }
      else { s_B = max((int)(m >> 12), 1); s_n = (int)(m & 0xFFFu); }
    }
  }
  __syncthreads();
  const int B = s_B;
  const int n = min(s_n, KTOP);

  ((uint4*)scur)[tid] = ((const uint4*)sstart)[tid];     // cursors
  __syncthreads();

  // ---- scatter survivors (bin >= B) into counting slots
  if (det) {
    for (int sg = wv; sg < NREG; sg += 16) {
      const u32 len = s_plen[sg];
      const uint2* seg = cand_det + ((size_t)b * NREG + sg) * REG_ENT;
      for (u32 i = lane; i < len; i += 64) {
        uint2 e = seg[i]; int bin = score_bin(e.x);
        if (bin >= B) { u32 sl = atomicAdd(&scur[bin], 1u);
          if (sl < (u32)KTOP) skey[sl] = ((u64)e.x << 32) | (u32)(~e.y); }
      }
    }
  } else if (!fb) {
    for (u32 i = tid; i < c0; i += 1024) {
      uint2 e = cb[OFF0 + i]; int bin = score_bin(e.x);
      if (bin >= B) { u32 sl = atomicAdd(&scur[bin], 1u);
        if (sl < (u32)KTOP) skey[sl] = ((u64)e.x << 32) | (u32)(~e.y); }
    }
    if (RL >= 1) for (u32 i = tid; i < c1; i += 1024) {
      uint2 e = cb[OFF1 + i]; int bin = score_bin(e.x);
      if (bin >= B) { u32 sl = atomicAdd(&scur[bin], 1u);
        if (sl < (u32)KTOP) skey[sl] = ((u64)e.x << 32) | (u32)(~e.y); }
    }
    if (RL >= 2) for (u32 i = tid; i < c2; i += 1024) {
      uint2 e = cb[OFF2 + i]; int bin = score_bin(e.x);
      if (bin >= B) { u32 sl = atomicAdd(&scur[bin], 1u);
        if (sl < (u32)KTOP) skey[sl] = ((u64)e.x << 32) | (u32)(~e.y); }
    }
    if (RL >= 3) for (u32 i = tid; i < c3; i += 1024) {
      uint2 e = cb[OFF3 + i]; int bin = score_bin(e.x);
      if (bin >= B) { u32 sl = atomicAdd(&scur[bin], 1u);
        if (sl < (u32)KTOP) skey[sl] = ((u64)e.x << 32) | (u32)(~e.y); }
    }
    if (RL >= 4) for (u32 i = tid; i < c4; i += 1024) {
      uint2 e = cb[OFF4 + i]; int bin = score_bin(e.x);
      if (bin >= B) { u32 sl = atomicAdd(&scur[bin], 1u);
        if (sl < (u32)KTOP) skey[sl] = ((u64)e.x << 32) | (u32)(~e.y); }
    }
  } else {
    for (int P = tid; P < NPAIR; P += 1024) {
      u32 b0, b1, gi0, gi1;
      score_pair(P, b, p2, p3, p4, p5, b0, b1, gi0, gi1);
      if (b0) { int bin = score_bin(b0);
        if (bin >= B) { u32 sl = atomicAdd(&scur[bin], 1u);
          if (sl < (u32)KTOP) skey[sl] = ((u64)b0 << 32) | (u32)(~gi0); } }
      if (b1) { int bin = score_bin(b1);
        if (bin >= B) { u32 sl = atomicAdd(&scur[bin], 1u);
          if (sl < (u32)KTOP) skey[sl] = ((u64)b1 << 32) | (u32)(~gi1); } }
    }
  }
  __syncthreads();

  // ---- exact rank sort within bins (barrier-free)
  for (int s = tid; s < n; s += 1024) {
    u64 k = skey[s];
    int bin = score_bin((u32)(k >> 32));
    int st = (int)sstart[bin];
    int en = (int)scur[bin];
    u32 r = 0;
    for (int j = st; j < en; ++j) r += (skey[j] > k) ? 1u : 0u;
    skey2[st + r] = k;
  }
  __syncthreads();

  const int Wn = min(n, WIN);

  // ---- window boxes
  if (tid < WIN) {
    sbox[tid] = (tid < Wn) ? decode_box_from_gidx(~(u32)skey2[tid], b, p2, p3, p4, p5)
                           : make_float4(0.f, 0.f, 0.f, 0.f);
  }
  __syncthreads();

  // ---- IoU bitmask matrix; row = tid&255, word = tid>>8 (broadcast reads)
  {
    int row = tid & 255, word = tid >> 8;
    u64 bits = 0;
    if (row < Wn) {
      float4 A = sbox[row];
      int j0 = word * 64;
      int je = min(64, Wn - j0);
      for (int j = 0; j < je; ++j)
        if (iou_gt(A, sbox[j0 + j])) bits |= (1ull << j);
    }
    smat[word * 256 + row] = bits;
  }
  __syncthreads();

  // ---- greedy selection on wave 0: all-static register state, deferred writes
  if (tid < 64) {
    u64 mA0 = smat[0*256 +   0 + lane], mA1 = smat[1*256 +   0 + lane],
        mA2 = smat[2*256 +   0 + lane], mA3 = smat[3*256 +   0 + lane];
    u64 mB0 = smat[0*256 +  64 + lane], mB1 = smat[1*256 +  64 + lane],
        mB2 = smat[2*256 +  64 + lane], mB3 = smat[3*256 +  64 + lane];
    u64 mC0 = smat[0*256 + 128 + lane], mC1 = smat[1*256 + 128 + lane],
        mC2 = smat[2*256 + 128 + lane], mC3 = smat[3*256 + 128 + lane];
    u64 mD0 = smat[0*256 + 192 + lane], mD1 = smat[1*256 + 192 + lane],
        mD2 = smat[2*256 + 192 + lane], mD3 = smat[3*256 + 192 + lane];

    u64 live0 = (Wn >=  64) ? ~0ull : (Wn >   0 ? ((1ull << (Wn -   0)) - 1ull) : 0ull);
    u64 live1 = (Wn >= 128) ? ~0ull : (Wn >  64 ? ((1ull << (Wn -  64)) - 1ull) : 0ull);
    u64 live2 = (Wn >= 192) ? ~0ull : (Wn > 128 ? ((1ull << (Wn - 128)) - 1ull) : 0ull);
    u64 live3 = (Wn >= 256) ? ~0ull : (Wn > 192 ? ((1ull << (Wn - 192)) - 1ull) : 0ull);
    int sel = 0;

    while (live0 && sel < 100) {
      int j = (int)__ffsll(live0) - 1;
      u64 r0 = shfl_u64(mA0, j), r1 = shfl_u64(mA1, j),
          r2 = shfl_u64(mA2, j), r3 = shfl_u64(mA3, j);
      live0 &= ~r0; live1 &= ~r1; live2 &= ~r2; live3 &= ~r3;
      live0 &= ~(1ull << j);
      if (lane == 0) s_sellist[sel] = (u32)j;
      sel++;
    }
    while (live1 && sel < 100) {
      int j = (int)__ffsll(live1) - 1;
      u64 r0 = shfl_u64(mB0, j), r1 = shfl_u64(mB1, j),
          r2 = shfl_u64(mB2, j), r3 = shfl_u64(mB3, j);
      live0 &= ~r0; live1 &= ~r1; live2 &= ~r2; live3 &= ~r3;
      live1 &= ~(1ull << j);
      if (lane == 0) s_sellist[sel] = (u32)(64 + j);
      sel++;
    }
    while (live2 && sel < 100) {
      int j = (int)__ffsll(live2) - 1;
      u64 r0 = shfl_u64(mC0, j), r1 = shfl_u64(mC1, j),
          r2 = shfl_u64(mC2, j), r3 = shfl_u64(mC3, j);
      live0 &= ~r0; live1 &= ~r1; live2 &= ~r2; live3 &= ~r3;
      live2 &= ~(1ull << j);
      if (lane == 0) s_sellist[sel] = (u32)(128 + j);
      sel++;
    }
    while (live3 && sel < 100) {
      int j = (int)__ffsll(live3) - 1;
      u64 r0 = shfl_u64(mD0, j), r1 = shfl_u64(mD1, j),
          r2 = shfl_u64(mD2, j), r3 = shfl_u64(mD3, j);
      live0 &= ~r0; live1 &= ~r1; live2 &= ~r2; live3 &= ~r3;
      live3 &= ~(1ull << j);
      if (lane == 0) s_sellist[sel] = (u32)(192 + j);
      sel++;
    }
    if (lane == 0) {
      s_misc[2] = sel;
      s_misc[3] = (sel < 100 && n > WIN) ? 1 : 0;
    }
  }
  __syncthreads();

  // ---- parallel deferred write of selected boxes
  {
    const int nsel0 = s_misc[2];
    if (tid < nsel0) {
      int p = (int)s_sellist[tid];
      u64 k = skey2[p];
      float4 box = sbox[p];
      selbox[tid] = box;
      float* orow = out + (size_t)b * 500 + (size_t)tid * 5;
      orow[0] = box.x; orow[1] = box.y; orow[2] = box.z; orow[3] = box.w;
      orow[4] = __uint_as_float((u32)(k >> 32));
    }
  }
  __syncthreads();

  // ---- exact slow path beyond the window (statistically never taken)
  if (s_misc[3]) {
    if (tid < 64) {
      int sel = s_misc[2];
      for (int p = WIN; p < n && sel < 100; ++p) {
        u64 k = skey2[p];
        float4 box = decode_box_from_gidx(~(u32)k, b, p2, p3, p4, p5);
        bool hit = false;
        if (lane < sel) hit = iou_gt(selbox[lane], box);
        if (lane + 64 < sel) hit = hit || iou_gt(selbox[lane + 64], box);
        u64 anyhit = __ballot(hit);
        if (anyhit == 0ull) {
          if (lane == 0) {
            selbox[sel] = box;
            float sc = __uint_as_float((u32)(k >> 32));
            float* orow = out + (size_t)b * 500 + (size_t)sel * 5;
            orow[0] = box.x; orow[1] = box.y; orow[2] = box.z; orow[3] = box.w; orow[4] = sc;
          }
          sel++;
        }
      }
      if (lane == 0) s_misc[2] = sel;
    }
  }
  __syncthreads();

  // ---- zero-fill remaining rows
  const int nsel = s_misc[2];
  for (int i = tid; i < (100 - nsel) * 5; i += 1024)
    out[(size_t)b * 500 + (size_t)nsel * 5 + i] = 0.0f;
}

// ---------------------------------------------------------------- launch
extern "C" void kernel_launch(void* const* d_in, const int* in_sizes, int n_in,
                              void* d_out, int out_size, void* d_ws, size_t ws_size,
                              hipStream_t stream) {
  const float* p2 = (const float*)d_in[0];
  const float* p3 = (const float*)d_in[1];
  const float* p4 = (const float*)d_in[2];
  const float* p5 = (const float*)d_in[3];
  float* out = (float*)d_out;

  unsigned char* w = (unsigned char*)d_ws;
  u32*   counters = (u32*)w;                          // legacy path
  uint2* cand_old = (uint2*)(w + WS_CAND_OLD);        // legacy path
  u32*   cnttab   = (u32*)w;                          // det path
  uint2* cand_det = (uint2*)(w + WS_CANDDET);         // det path

  const int det = (ws_size >= (size_t)NEED_DET) ? 1 : 0;
  if (!det) hipMemsetAsync(counters, 0, 32 * CSTRIDE * sizeof(u32), stream);
  decode_kernel<<<dim3(NREG, 32), 512, 0, stream>>>(p2, p3, p4, p5,
                                                    counters, cand_old,
                                                    cnttab, cand_det, det);
  mega_kernel<<<32, 1024, 0, stream>>>(counters, cand_old, cnttab, cand_det,
                                       p2, p3, p4, p5, out, det);
}